// Round 11
// baseline (203.145 us; speedup 1.0000x reference)
//
#include <hip/hip_runtime.h>

#define NPTS 50000
#define MPTS 50000
#define HN 32
#define KCD 960      // 15 kernel pts * 64 Cin
#define PSTRIDE 968  // fused-path P_sh stride (R6/R9-proven)

typedef float f32x4 __attribute__((ext_vector_type(4)));
typedef short s16x8 __attribute__((ext_vector_type(8)));

__device__ __forceinline__ unsigned short bf_rne(float x) {
    union { float f; unsigned u; } v; v.f = x;
    unsigned r = v.u + 0x7fffu + ((v.u >> 16) & 1u);
    return (unsigned short)(r >> 16);
}
__device__ __forceinline__ unsigned short bf_trunc(float x) {
    union { float f; unsigned u; } v; v.f = x;
    return (unsigned short)(v.u >> 16);
}
__device__ __forceinline__ unsigned pack_bf(float lo, float hi) {
    union { float f; unsigned u; } a, b; a.f = lo; b.f = hi;
    return __builtin_amdgcn_perm(b.u, a.u, 0x07060302u);
}
__device__ __forceinline__ unsigned pack_rne(float lo, float hi) {
    return ((unsigned)bf_rne(hi) << 16) | (unsigned)bf_rne(lo);
}
__device__ __forceinline__ unsigned pack_lo16(unsigned a, unsigned b) {
    return __builtin_amdgcn_perm(b, a, 0x05040100u);
}
__device__ __forceinline__ unsigned pack_hi16(unsigned a, unsigned b) {
    return __builtin_amdgcn_perm(b, a, 0x07060302u);
}

// ---- prep kernels (unchanged from R9) ---------------------------------------
__global__ __launch_bounds__(256) void prep_bf(const float* __restrict__ w,
                                               const float* __restrict__ feats,
                                               unsigned short* __restrict__ WT,
                                               unsigned char* __restrict__ signs,
                                               unsigned short* __restrict__ fbf) {
    int b = blockIdx.x;
    if (b < 240) {
        int t = b * 256 + threadIdx.x;
        int kc = t >> 6, d = t & 63;
        WT[d * KCD + kc] = bf_rne(w[t]);
    } else {
        int t = threadIdx.x;
        int p = t >> 4, r = t & 15;
        int n = (b - 240) * 16 + p;
        const float* src = feats + (size_t)n * 64 + r;
        float c0 = src[0], c1 = src[16], c2 = src[32], c3 = src[48];
        float s = c0 + c1 + c2 + c3;
        s += __shfl_xor(s, 1); s += __shfl_xor(s, 2);
        s += __shfl_xor(s, 4); s += __shfl_xor(s, 8);
        if (r == 0) signs[n] = (s > 0.f) ? 1 : 0;
        uint2 o; o.x = pack_rne(c0, c1); o.y = pack_rne(c2, c3);
        *(uint2*)(fbf + (size_t)n * 64 + r * 4) = o;
    }
}

__global__ __launch_bounds__(256) void prep_f32(const float* __restrict__ w,
                                                const float* __restrict__ feats,
                                                unsigned short* __restrict__ WT,
                                                unsigned char* __restrict__ signs) {
    int b = blockIdx.x;
    if (b < 240) {
        int t = b * 256 + threadIdx.x;
        int kc = t >> 6, d = t & 63;
        WT[d * KCD + kc] = bf_rne(w[t]);
    } else {
        int lane = threadIdx.x & 63, wv = threadIdx.x >> 6;
        int r4 = lane >> 4, c16 = lane & 15;
        int n = (b - 240) * 16 + wv * 4 + r4;
        float4 v = *(const float4*)(feats + (size_t)n * 64 + c16 * 4);
        float s = v.x + v.y + v.z + v.w;
        s += __shfl_xor(s, 1); s += __shfl_xor(s, 2);
        s += __shfl_xor(s, 4); s += __shfl_xor(s, 8);
        if (c16 == 0) signs[n] = (s > 0.f) ? 1 : 0;
    }
}

// ---- SPLIT kernel P1: gather + influence + first MFMA -> P (global, bf16) ---
// No cross-wave coupling: waves flush their own queries through a 2KB pbuf.
// inv_nnum folded into P so P2 is a pure GEMM.
__global__ __launch_bounds__(256, 6)
void kpconv_p1(const float* __restrict__ q_points,
               const float* __restrict__ s_points,
               const unsigned short* __restrict__ fbf,
               const int* __restrict__ ni,
               const float* __restrict__ kpts,
               const unsigned char* __restrict__ signs,
               unsigned short* __restrict__ P) {
    __shared__ __align__(16) unsigned short pbuf[4][1032];  // per-wave repack
    __shared__ __align__(16) float rpos_sh[4][3][32];
    __shared__ int ni_sh[4][4][32];
    __shared__ float kp_sh[16][3];
    __shared__ float q_sh[16][3];
    // ~12.3 KB total; occupancy VGPR-capped (launch_bounds 6 -> <=85 VGPR)

    int tid = threadIdx.x, w = tid >> 6, lane = tid & 63;
    int m_base = blockIdx.x << 4;

    if (tid < 48) {
        kp_sh[tid / 3][tid % 3] = (tid < 45) ? kpts[tid] : 1e9f;
        q_sh[tid / 3][tid % 3] = q_points[m_base * 3 + tid];
    }
    __syncthreads();

    int h = lane & 31;
    int row = lane & 15, quad = lane >> 4, kq = quad << 3;
    int h2 = lane >> 1, half = lane & 1;

    float kx = kp_sh[row][0], ky = kp_sh[row][1], kz = kp_sh[row][2];

    float tkx[8], tky[8], tkz[8];
    #pragma unroll
    for (int j = 0; j < 8; ++j) {
        int k = half * 8 + j;
        tkx[j] = kp_sh[k][0]; tky[j] = kp_sh[k][1]; tkz[j] = kp_sh[k][2];
    }

    int idx4[4]; float rxa[4], rya[4], rza[4]; unsigned char sg4[4];
    #pragma unroll
    for (int mi = 0; mi < 4; ++mi)
        idx4[mi] = ni[(m_base + mi * 4 + w) * HN + h];
    #pragma unroll
    for (int mi = 0; mi < 4; ++mi) {
        int m_l = mi * 4 + w;
        bool valid = idx4[mi] < NPTS;
        const float* sp = s_points + (size_t)(valid ? idx4[mi] : 0) * 3;
        float px = sp[0], py = sp[1], pz = sp[2];
        unsigned char sg = signs[valid ? idx4[mi] : 0];
        rxa[mi] = (valid ? px : 1e6f) - q_sh[m_l][0];
        rya[mi] = (valid ? py : 1e6f) - q_sh[m_l][1];
        rza[mi] = (valid ? pz : 1e6f) - q_sh[m_l][2];
        sg4[mi] = valid ? sg : 0;
    }

    float inv4[4];
    #pragma unroll
    for (int mi = 0; mi < 4; ++mi) {
        float rx2 = __shfl(rxa[mi], h2);
        float ry2 = __shfl(rya[mi], h2);
        float rz2 = __shfl(rza[mi], h2);
        int idx2 = __shfl(idx4[mi], h2);
        int av = 0;
        #pragma unroll
        for (int j = 0; j < 8; ++j) {
            float dx = rx2 - tkx[j], dy = ry2 - tky[j], dz = rz2 - tkz[j];
            float d2 = dx * dx + dy * dy + dz * dz;
            av |= (d2 < 1.f) ? 1 : 0;
        }
        av |= __shfl_xor(av, 1);
        bool alive = (idx2 < NPTS) && (av != 0);
        if (half == 0) ni_sh[w][mi][h2] = alive ? idx2 : NPTS;

        unsigned long long pm = __ballot((lane < 32) && (idx4[mi] < NPTS) && sg4[mi]);
        int cnt = __popcll(pm);
        inv4[mi] = 1.f / (float)(cnt < 1 ? 1 : cnt);   // wave-uniform, in regs
    }

    #pragma unroll
    for (int mi = 0; mi < 4; ++mi) {
        int m_l = mi * 4 + w;
        if (lane < 32) {
            rpos_sh[w][0][h] = rxa[mi];
            rpos_sh[w][1][h] = rya[mi];
            rpos_sh[w][2][h] = rza[mi];
        }

        unsigned d0[8], d1[8];
        #pragma unroll
        for (int j = 0; j < 8; ++j) {
            int idxj = ni_sh[w][mi][kq + j];
            d0[j] = 0u; d1[j] = 0u;
            if (idxj < NPTS) {
                uint2 v = *(const uint2*)(fbf + (size_t)idxj * 64 + row * 4);
                d0[j] = v.x; d1[j] = v.y;
            }
        }

        float4 ra0 = *(const float4*)&rpos_sh[w][0][kq];
        float4 ra1 = *(const float4*)&rpos_sh[w][0][kq + 4];
        float4 rb0 = *(const float4*)&rpos_sh[w][1][kq];
        float4 rb1 = *(const float4*)&rpos_sh[w][1][kq + 4];
        float4 rc0 = *(const float4*)&rpos_sh[w][2][kq];
        float4 rc1 = *(const float4*)&rpos_sh[w][2][kq + 4];
        float hx[8] = {ra0.x, ra0.y, ra0.z, ra0.w, ra1.x, ra1.y, ra1.z, ra1.w};
        float hy[8] = {rb0.x, rb0.y, rb0.z, rb0.w, rb1.x, rb1.y, rb1.z, rb1.w};
        float hz[8] = {rc0.x, rc0.y, rc0.z, rc0.w, rc1.x, rc1.y, rc1.z, rc1.w};
        float infl[8];
        #pragma unroll
        for (int j = 0; j < 8; ++j) {
            float dx = hx[j] - kx, dy = hy[j] - ky, dz = hz[j] - kz;
            float d2 = dx * dx + dy * dy + dz * dz;
            float f = 1.f - sqrtf(d2);
            infl[j] = f > 0.f ? f : 0.f;
        }
        union { unsigned u[4]; s16x8 v; } af;
        #pragma unroll
        for (int p = 0; p < 4; ++p) af.u[p] = pack_bf(infl[2 * p], infl[2 * p + 1]);

        #pragma unroll
        for (int ch = 0; ch < 4; ++ch) {
            union { unsigned u[4]; s16x8 v; } bfr;
            #pragma unroll
            for (int p = 0; p < 4; ++p) {
                unsigned a = (ch < 2) ? d0[2 * p] : d1[2 * p];
                unsigned b = (ch < 2) ? d0[2 * p + 1] : d1[2 * p + 1];
                bfr.u[p] = (ch & 1) ? pack_hi16(a, b) : pack_lo16(a, b);
            }
            f32x4 acc = {0.f, 0.f, 0.f, 0.f};
            acc = __builtin_amdgcn_mfma_f32_16x16x32_bf16(af.v, bfr.v, acc, 0, 0, 0);
            int cc = ch * 16 + row;
            #pragma unroll
            for (int r = 0; r < 4; ++r) {
                int k2 = quad * 4 + r;   // unpredicated: k2==15 lands in cols 960..1023
                int col = (k2 << 6) | (cc ^ ((k2 >> 2) << 4));
                pbuf[w][col] = bf_trunc(acc[r] * inv4[mi]);
            }
        }

        // flush this query's 1920B to P, coalesced b128 (2 rounds, same wave ->
        // DS in-order, no barrier). Reader unswizzles the quad-XOR pattern.
        {
            unsigned short* Pr = P + (size_t)(m_base + m_l) * KCD;
            int c8 = lane;                       // chunks of 8 shorts, 0..119 used
            int k = c8 >> 3, c0 = (c8 & 7) << 3;
            int swz = (k << 6) | (c0 ^ (((k >> 2) & 3) << 4));
            s16x8 v0 = *(const s16x8*)&pbuf[w][swz];
            *(s16x8*)(Pr + c8 * 8) = v0;
            int c8b = 64 + lane;
            if (c8b < 120) {
                int kb = c8b >> 3, c0b = (c8b & 7) << 3;
                int swzb = (kb << 6) | (c0b ^ (((kb >> 2) & 3) << 4));
                s16x8 v1 = *(const s16x8*)&pbuf[w][swzb];
                *(s16x8*)(Pr + c8b * 8) = v1;
            }
        }
    }
}

// ---- SPLIT kernel P2: pure GEMM out(50000x64) = P(50000x960) @ WT^T ---------
// A-frags straight from global (16 rows x 64B segments), zero LDS.
__global__ __launch_bounds__(256, 8)
void kpconv_p2(const unsigned short* __restrict__ P,
               const unsigned short* __restrict__ WT,
               float* __restrict__ out) {
    int tid = threadIdx.x, w = tid >> 6, lane = tid & 63;
    int row = lane & 15, quad = lane >> 4, kq = quad << 3;
    int m_base = blockIdx.x << 4;
    int dbase = w << 4;
    const unsigned short* ap = P + (size_t)(m_base + row) * KCD + kq;
    const unsigned short* bp = WT + (size_t)(dbase + row) * KCD + kq;
    f32x4 acc = {0.f, 0.f, 0.f, 0.f};
    #pragma unroll 6
    for (int s = 0; s < 30; ++s) {
        s16x8 a = *(const s16x8*)(ap + s * 32);
        s16x8 b = *(const s16x8*)(bp + s * 32);
        acc = __builtin_amdgcn_mfma_f32_16x16x32_bf16(a, b, acc, 0, 0, 0);
    }
    #pragma unroll
    for (int r = 0; r < 4; ++r) {
        int m_l = quad * 4 + r;
        out[(size_t)(m_base + m_l) * 64 + dbase + row] = acc[r];
    }
}

// ---- fused fallback (R9, proven 150.4 us) -----------------------------------
template <bool USE_BF>
__device__ __forceinline__
void kpconv_body(const float* __restrict__ q_points,
                 const float* __restrict__ s_points,
                 const float* __restrict__ s_feats,
                 const unsigned short* __restrict__ fbf,
                 const int* __restrict__ ni,
                 const float* __restrict__ kpts,
                 const unsigned short* __restrict__ WT,
                 const unsigned char* __restrict__ signs,
                 float* __restrict__ out) {
    __shared__ __align__(16) unsigned short P_sh[16][PSTRIDE];
    __shared__ __align__(16) float rpos_sh[4][3][32];
    __shared__ int ni_sh[4][4][32];
    __shared__ float kp_sh[16][3];
    __shared__ float q_sh[16][3];
    __shared__ float inv_nnum[16];

    int tid = threadIdx.x, w = tid >> 6, lane = tid & 63;
    int m_base = blockIdx.x << 4;

    if (tid < 48) {
        kp_sh[tid / 3][tid % 3] = (tid < 45) ? kpts[tid] : 1e9f;
        q_sh[tid / 3][tid % 3] = q_points[m_base * 3 + tid];
    }
    __syncthreads();

    int h = lane & 31;
    int row = lane & 15, quad = lane >> 4, kq = quad << 3;
    int h2 = lane >> 1, half = lane & 1;

    float kx = kp_sh[row][0], ky = kp_sh[row][1], kz = kp_sh[row][2];

    float tkx[8], tky[8], tkz[8];
    #pragma unroll
    for (int j = 0; j < 8; ++j) {
        int k = half * 8 + j;
        tkx[j] = kp_sh[k][0]; tky[j] = kp_sh[k][1]; tkz[j] = kp_sh[k][2];
    }

    int idx4[4]; float rxa[4], rya[4], rza[4]; unsigned char sg4[4];
    #pragma unroll
    for (int mi = 0; mi < 4; ++mi)
        idx4[mi] = ni[(m_base + mi * 4 + w) * HN + h];
    #pragma unroll
    for (int mi = 0; mi < 4; ++mi) {
        int m_l = mi * 4 + w;
        bool valid = idx4[mi] < NPTS;
        const float* sp = s_points + (size_t)(valid ? idx4[mi] : 0) * 3;
        float px = sp[0], py = sp[1], pz = sp[2];
        unsigned char sg = signs[valid ? idx4[mi] : 0];
        rxa[mi] = (valid ? px : 1e6f) - q_sh[m_l][0];
        rya[mi] = (valid ? py : 1e6f) - q_sh[m_l][1];
        rza[mi] = (valid ? pz : 1e6f) - q_sh[m_l][2];
        sg4[mi] = valid ? sg : 0;
    }

    #pragma unroll
    for (int mi = 0; mi < 4; ++mi) {
        float rx2 = __shfl(rxa[mi], h2);
        float ry2 = __shfl(rya[mi], h2);
        float rz2 = __shfl(rza[mi], h2);
        int idx2 = __shfl(idx4[mi], h2);
        int av = 0;
        #pragma unroll
        for (int j = 0; j < 8; ++j) {
            float dx = rx2 - tkx[j], dy = ry2 - tky[j], dz = rz2 - tkz[j];
            float d2 = dx * dx + dy * dy + dz * dz;
            av |= (d2 < 1.f) ? 1 : 0;
        }
        av |= __shfl_xor(av, 1);
        bool alive = (idx2 < NPTS) && (av != 0);
        if (half == 0) ni_sh[w][mi][h2] = alive ? idx2 : NPTS;

        unsigned long long pm = __ballot((lane < 32) && (idx4[mi] < NPTS) && sg4[mi]);
        if (lane == 0) {
            int cnt = __popcll(pm);
            inv_nnum[mi * 4 + w] = 1.f / (float)(cnt < 1 ? 1 : cnt);
        }
    }

    #pragma unroll
    for (int mi = 0; mi < 4; ++mi) {
        int m_l = mi * 4 + w;
        if (lane < 32) {
            rpos_sh[w][0][h] = rxa[mi];
            rpos_sh[w][1][h] = rya[mi];
            rpos_sh[w][2][h] = rza[mi];
        }

        float g0[8], g1[8], g2[8], g3[8];
        unsigned d0[8], d1[8];
        #pragma unroll
        for (int j = 0; j < 8; ++j) {
            int idxj = ni_sh[w][mi][kq + j];
            if (USE_BF) {
                d0[j] = 0u; d1[j] = 0u;
                if (idxj < NPTS) {
                    uint2 v = *(const uint2*)(fbf + (size_t)idxj * 64 + row * 4);
                    d0[j] = v.x; d1[j] = v.y;
                }
            } else {
                g0[j] = 0.f; g1[j] = 0.f; g2[j] = 0.f; g3[j] = 0.f;
                if (idxj < NPTS) {
                    const float* fp = s_feats + (size_t)idxj * 64 + row;
                    g0[j] = fp[0]; g1[j] = fp[16]; g2[j] = fp[32]; g3[j] = fp[48];
                }
            }
        }

        float4 ra0 = *(const float4*)&rpos_sh[w][0][kq];
        float4 ra1 = *(const float4*)&rpos_sh[w][0][kq + 4];
        float4 rb0 = *(const float4*)&rpos_sh[w][1][kq];
        float4 rb1 = *(const float4*)&rpos_sh[w][1][kq + 4];
        float4 rc0 = *(const float4*)&rpos_sh[w][2][kq];
        float4 rc1 = *(const float4*)&rpos_sh[w][2][kq + 4];
        float hx[8] = {ra0.x, ra0.y, ra0.z, ra0.w, ra1.x, ra1.y, ra1.z, ra1.w};
        float hy[8] = {rb0.x, rb0.y, rb0.z, rb0.w, rb1.x, rb1.y, rb1.z, rb1.w};
        float hz[8] = {rc0.x, rc0.y, rc0.z, rc0.w, rc1.x, rc1.y, rc1.z, rc1.w};
        float infl[8];
        #pragma unroll
        for (int j = 0; j < 8; ++j) {
            float dx = hx[j] - kx, dy = hy[j] - ky, dz = hz[j] - kz;
            float d2 = dx * dx + dy * dy + dz * dz;
            float f = 1.f - sqrtf(d2);
            infl[j] = f > 0.f ? f : 0.f;
        }
        union { unsigned u[4]; s16x8 v; } af;
        #pragma unroll
        for (int p = 0; p < 4; ++p) af.u[p] = pack_bf(infl[2 * p], infl[2 * p + 1]);

        #pragma unroll
        for (int ch = 0; ch < 4; ++ch) {
            union { unsigned u[4]; s16x8 v; } bfr;
            if (USE_BF) {
                #pragma unroll
                for (int p = 0; p < 4; ++p) {
                    unsigned a = (ch < 2) ? d0[2 * p] : d1[2 * p];
                    unsigned b = (ch < 2) ? d0[2 * p + 1] : d1[2 * p + 1];
                    bfr.u[p] = (ch & 1) ? pack_hi16(a, b) : pack_lo16(a, b);
                }
            } else {
                const float* gs = (ch == 0) ? g0 : (ch == 1) ? g1 : (ch == 2) ? g2 : g3;
                #pragma unroll
                for (int p = 0; p < 4; ++p) bfr.u[p] = pack_bf(gs[2 * p], gs[2 * p + 1]);
            }
            f32x4 acc = {0.f, 0.f, 0.f, 0.f};
            acc = __builtin_amdgcn_mfma_f32_16x16x32_bf16(af.v, bfr.v, acc, 0, 0, 0);
            int cc = ch * 16 + row;
            #pragma unroll
            for (int r = 0; r < 4; ++r) {
                int k2 = quad * 4 + r;
                if (k2 < 15) {
                    int col = (k2 << 6) | (cc ^ ((k2 >> 2) << 4));
                    P_sh[m_l][col] = bf_trunc(acc[r]);
                }
            }
        }
    }
    __syncthreads();

    {
        int dbase = w << 4;
        f32x4 acc = {0.f, 0.f, 0.f, 0.f};
        const unsigned short* wtp = WT + (size_t)(dbase + row) * KCD + kq;
        #pragma unroll 6
        for (int s = 0; s < 30; ++s) {
            int k = s >> 1;
            int c0 = ((s & 1) << 5) + kq;
            int cx = c0 ^ (((k >> 2) & 3) << 4);
            s16x8 a = *(const s16x8*)&P_sh[row][(k << 6) | cx];
            s16x8 b = *(const s16x8*)&wtp[s * 32];
            acc = __builtin_amdgcn_mfma_f32_16x16x32_bf16(a, b, acc, 0, 0, 0);
        }
        #pragma unroll
        for (int r = 0; r < 4; ++r) {
            int m_l = quad * 4 + r;
            out[(size_t)(m_base + m_l) * 64 + dbase + row] = acc[r] * inv_nnum[m_l];
        }
    }
}

__global__ __launch_bounds__(256, 4)
void kpconv_main_bf(const float* __restrict__ q, const float* __restrict__ sp,
                    const unsigned short* __restrict__ fbf,
                    const int* __restrict__ ni, const float* __restrict__ kp,
                    const unsigned short* __restrict__ WT,
                    const unsigned char* __restrict__ signs,
                    float* __restrict__ out) {
    kpconv_body<true>(q, sp, nullptr, fbf, ni, kp, WT, signs, out);
}

__global__ __launch_bounds__(256, 4)
void kpconv_main_f32(const float* __restrict__ q, const float* __restrict__ sp,
                     const float* __restrict__ sf,
                     const int* __restrict__ ni, const float* __restrict__ kp,
                     const unsigned short* __restrict__ WT,
                     const unsigned char* __restrict__ signs,
                     float* __restrict__ out) {
    kpconv_body<false>(q, sp, sf, nullptr, ni, kp, WT, signs, out);
}

extern "C" void kernel_launch(void* const* d_in, const int* in_sizes, int n_in,
                              void* d_out, int out_size, void* d_ws, size_t ws_size,
                              hipStream_t stream) {
    const float* q  = (const float*)d_in[0];
    const float* sp = (const float*)d_in[1];
    const float* sf = (const float*)d_in[2];
    const int*   ni = (const int*)d_in[3];
    const float* kp = (const float*)d_in[4];
    const float* wt = (const float*)d_in[5];
    float* out = (float*)d_out;

    unsigned short* WT = (unsigned short*)d_ws;                    // 122880 B
    unsigned char* signs = (unsigned char*)d_ws + 122880;          // 50000 B
    const size_t off_fbf = 172928;
    unsigned short* fbf = (unsigned short*)((char*)d_ws + off_fbf); // 6.4 MB
    const size_t off_P = off_fbf + (size_t)NPTS * 64 * 2;           // 6572928
    unsigned short* P = (unsigned short*)((char*)d_ws + off_P);     // 96 MB
    const size_t need_bf = off_P;
    const size_t need_split = off_P + (size_t)MPTS * KCD * 2;

    if (ws_size >= need_split) {
        hipLaunchKernelGGL(prep_bf, dim3(240 + NPTS / 16), dim3(256), 0, stream,
                           wt, sf, WT, signs, fbf);
        hipLaunchKernelGGL(kpconv_p1, dim3(MPTS / 16), dim3(256), 0, stream,
                           q, sp, fbf, ni, kp, signs, P);
        hipLaunchKernelGGL(kpconv_p2, dim3(MPTS / 16), dim3(256), 0, stream,
                           P, WT, out);
    } else if (ws_size >= need_bf) {
        hipLaunchKernelGGL(prep_bf, dim3(240 + NPTS / 16), dim3(256), 0, stream,
                           wt, sf, WT, signs, fbf);
        hipLaunchKernelGGL(kpconv_main_bf, dim3(MPTS / 16), dim3(256), 0, stream,
                           q, sp, fbf, ni, kp, WT, signs, out);
    } else {
        hipLaunchKernelGGL(prep_f32, dim3(240 + NPTS / 16), dim3(256), 0, stream,
                           wt, sf, WT, signs);
        hipLaunchKernelGGL(kpconv_main_f32, dim3(MPTS / 16), dim3(256), 0, stream,
                           q, sp, sf, ni, kp, WT, signs, out);
    }
}

// Round 12
// 178.075 us; speedup vs baseline: 1.1408x; 1.1408x over previous
//
#include <hip/hip_runtime.h>

#define NPTS 50000
#define MPTS 50000
#define HN 32
#define KCD 960      // 15 kernel pts * 64 Cin
#define PSTRIDE 968  // fused-path P_sh stride (R6/R9-proven)

typedef float f32x4 __attribute__((ext_vector_type(4)));
typedef short s16x8 __attribute__((ext_vector_type(8)));

__device__ __forceinline__ unsigned short bf_rne(float x) {
    union { float f; unsigned u; } v; v.f = x;
    unsigned r = v.u + 0x7fffu + ((v.u >> 16) & 1u);
    return (unsigned short)(r >> 16);
}
__device__ __forceinline__ unsigned short bf_trunc(float x) {
    union { float f; unsigned u; } v; v.f = x;
    return (unsigned short)(v.u >> 16);
}
__device__ __forceinline__ unsigned pack_bf(float lo, float hi) {
    union { float f; unsigned u; } a, b; a.f = lo; b.f = hi;
    return __builtin_amdgcn_perm(b.u, a.u, 0x07060302u);
}
__device__ __forceinline__ unsigned pack_rne(float lo, float hi) {
    return ((unsigned)bf_rne(hi) << 16) | (unsigned)bf_rne(lo);
}
__device__ __forceinline__ unsigned pack_lo16(unsigned a, unsigned b) {
    return __builtin_amdgcn_perm(b, a, 0x05040100u);
}
__device__ __forceinline__ unsigned pack_hi16(unsigned a, unsigned b) {
    return __builtin_amdgcn_perm(b, a, 0x07060302u);
}

// ---- prep kernels (unchanged) -----------------------------------------------
__global__ __launch_bounds__(256) void prep_bf(const float* __restrict__ w,
                                               const float* __restrict__ feats,
                                               unsigned short* __restrict__ WT,
                                               unsigned char* __restrict__ signs,
                                               unsigned short* __restrict__ fbf) {
    int b = blockIdx.x;
    if (b < 240) {
        int t = b * 256 + threadIdx.x;
        int kc = t >> 6, d = t & 63;
        WT[d * KCD + kc] = bf_rne(w[t]);
    } else {
        int t = threadIdx.x;
        int p = t >> 4, r = t & 15;
        int n = (b - 240) * 16 + p;
        const float* src = feats + (size_t)n * 64 + r;
        float c0 = src[0], c1 = src[16], c2 = src[32], c3 = src[48];
        float s = c0 + c1 + c2 + c3;
        s += __shfl_xor(s, 1); s += __shfl_xor(s, 2);
        s += __shfl_xor(s, 4); s += __shfl_xor(s, 8);
        if (r == 0) signs[n] = (s > 0.f) ? 1 : 0;
        uint2 o; o.x = pack_rne(c0, c1); o.y = pack_rne(c2, c3);
        *(uint2*)(fbf + (size_t)n * 64 + r * 4) = o;
    }
}

__global__ __launch_bounds__(256) void prep_f32(const float* __restrict__ w,
                                                const float* __restrict__ feats,
                                                unsigned short* __restrict__ WT,
                                                unsigned char* __restrict__ signs) {
    int b = blockIdx.x;
    if (b < 240) {
        int t = b * 256 + threadIdx.x;
        int kc = t >> 6, d = t & 63;
        WT[d * KCD + kc] = bf_rne(w[t]);
    } else {
        int lane = threadIdx.x & 63, wv = threadIdx.x >> 6;
        int r4 = lane >> 4, c16 = lane & 15;
        int n = (b - 240) * 16 + wv * 4 + r4;
        float4 v = *(const float4*)(feats + (size_t)n * 64 + c16 * 4);
        float s = v.x + v.y + v.z + v.w;
        s += __shfl_xor(s, 1); s += __shfl_xor(s, 2);
        s += __shfl_xor(s, 4); s += __shfl_xor(s, 8);
        if (c16 == 0) signs[n] = (s > 0.f) ? 1 : 0;
    }
}

// ---- SPLIT kernel P1 (unchanged from R11; measured ~32 us) ------------------
__global__ __launch_bounds__(256, 6)
void kpconv_p1(const float* __restrict__ q_points,
               const float* __restrict__ s_points,
               const unsigned short* __restrict__ fbf,
               const int* __restrict__ ni,
               const float* __restrict__ kpts,
               const unsigned char* __restrict__ signs,
               unsigned short* __restrict__ P) {
    __shared__ __align__(16) unsigned short pbuf[4][1032];
    __shared__ __align__(16) float rpos_sh[4][3][32];
    __shared__ int ni_sh[4][4][32];
    __shared__ float kp_sh[16][3];
    __shared__ float q_sh[16][3];

    int tid = threadIdx.x, w = tid >> 6, lane = tid & 63;
    int m_base = blockIdx.x << 4;

    if (tid < 48) {
        kp_sh[tid / 3][tid % 3] = (tid < 45) ? kpts[tid] : 1e9f;
        q_sh[tid / 3][tid % 3] = q_points[m_base * 3 + tid];
    }
    __syncthreads();

    int h = lane & 31;
    int row = lane & 15, quad = lane >> 4, kq = quad << 3;
    int h2 = lane >> 1, half = lane & 1;

    float kx = kp_sh[row][0], ky = kp_sh[row][1], kz = kp_sh[row][2];

    float tkx[8], tky[8], tkz[8];
    #pragma unroll
    for (int j = 0; j < 8; ++j) {
        int k = half * 8 + j;
        tkx[j] = kp_sh[k][0]; tky[j] = kp_sh[k][1]; tkz[j] = kp_sh[k][2];
    }

    int idx4[4]; float rxa[4], rya[4], rza[4]; unsigned char sg4[4];
    #pragma unroll
    for (int mi = 0; mi < 4; ++mi)
        idx4[mi] = ni[(m_base + mi * 4 + w) * HN + h];
    #pragma unroll
    for (int mi = 0; mi < 4; ++mi) {
        int m_l = mi * 4 + w;
        bool valid = idx4[mi] < NPTS;
        const float* sp = s_points + (size_t)(valid ? idx4[mi] : 0) * 3;
        float px = sp[0], py = sp[1], pz = sp[2];
        unsigned char sg = signs[valid ? idx4[mi] : 0];
        rxa[mi] = (valid ? px : 1e6f) - q_sh[m_l][0];
        rya[mi] = (valid ? py : 1e6f) - q_sh[m_l][1];
        rza[mi] = (valid ? pz : 1e6f) - q_sh[m_l][2];
        sg4[mi] = valid ? sg : 0;
    }

    float inv4[4];
    #pragma unroll
    for (int mi = 0; mi < 4; ++mi) {
        float rx2 = __shfl(rxa[mi], h2);
        float ry2 = __shfl(rya[mi], h2);
        float rz2 = __shfl(rza[mi], h2);
        int idx2 = __shfl(idx4[mi], h2);
        int av = 0;
        #pragma unroll
        for (int j = 0; j < 8; ++j) {
            float dx = rx2 - tkx[j], dy = ry2 - tky[j], dz = rz2 - tkz[j];
            float d2 = dx * dx + dy * dy + dz * dz;
            av |= (d2 < 1.f) ? 1 : 0;
        }
        av |= __shfl_xor(av, 1);
        bool alive = (idx2 < NPTS) && (av != 0);
        if (half == 0) ni_sh[w][mi][h2] = alive ? idx2 : NPTS;

        unsigned long long pm = __ballot((lane < 32) && (idx4[mi] < NPTS) && sg4[mi]);
        int cnt = __popcll(pm);
        inv4[mi] = 1.f / (float)(cnt < 1 ? 1 : cnt);
    }

    #pragma unroll
    for (int mi = 0; mi < 4; ++mi) {
        int m_l = mi * 4 + w;
        if (lane < 32) {
            rpos_sh[w][0][h] = rxa[mi];
            rpos_sh[w][1][h] = rya[mi];
            rpos_sh[w][2][h] = rza[mi];
        }

        unsigned d0[8], d1[8];
        #pragma unroll
        for (int j = 0; j < 8; ++j) {
            int idxj = ni_sh[w][mi][kq + j];
            d0[j] = 0u; d1[j] = 0u;
            if (idxj < NPTS) {
                uint2 v = *(const uint2*)(fbf + (size_t)idxj * 64 + row * 4);
                d0[j] = v.x; d1[j] = v.y;
            }
        }

        float4 ra0 = *(const float4*)&rpos_sh[w][0][kq];
        float4 ra1 = *(const float4*)&rpos_sh[w][0][kq + 4];
        float4 rb0 = *(const float4*)&rpos_sh[w][1][kq];
        float4 rb1 = *(const float4*)&rpos_sh[w][1][kq + 4];
        float4 rc0 = *(const float4*)&rpos_sh[w][2][kq];
        float4 rc1 = *(const float4*)&rpos_sh[w][2][kq + 4];
        float hx[8] = {ra0.x, ra0.y, ra0.z, ra0.w, ra1.x, ra1.y, ra1.z, ra1.w};
        float hy[8] = {rb0.x, rb0.y, rb0.z, rb0.w, rb1.x, rb1.y, rb1.z, rb1.w};
        float hz[8] = {rc0.x, rc0.y, rc0.z, rc0.w, rc1.x, rc1.y, rc1.z, rc1.w};
        float infl[8];
        #pragma unroll
        for (int j = 0; j < 8; ++j) {
            float dx = hx[j] - kx, dy = hy[j] - ky, dz = hz[j] - kz;
            float d2 = dx * dx + dy * dy + dz * dz;
            float f = 1.f - sqrtf(d2);
            infl[j] = f > 0.f ? f : 0.f;
        }
        union { unsigned u[4]; s16x8 v; } af;
        #pragma unroll
        for (int p = 0; p < 4; ++p) af.u[p] = pack_bf(infl[2 * p], infl[2 * p + 1]);

        #pragma unroll
        for (int ch = 0; ch < 4; ++ch) {
            union { unsigned u[4]; s16x8 v; } bfr;
            #pragma unroll
            for (int p = 0; p < 4; ++p) {
                unsigned a = (ch < 2) ? d0[2 * p] : d1[2 * p];
                unsigned b = (ch < 2) ? d0[2 * p + 1] : d1[2 * p + 1];
                bfr.u[p] = (ch & 1) ? pack_hi16(a, b) : pack_lo16(a, b);
            }
            f32x4 acc = {0.f, 0.f, 0.f, 0.f};
            acc = __builtin_amdgcn_mfma_f32_16x16x32_bf16(af.v, bfr.v, acc, 0, 0, 0);
            int cc = ch * 16 + row;
            #pragma unroll
            for (int r = 0; r < 4; ++r) {
                int k2 = quad * 4 + r;
                int col = (k2 << 6) | (cc ^ ((k2 >> 2) << 4));
                pbuf[w][col] = bf_trunc(acc[r] * inv4[mi]);
            }
        }

        {
            unsigned short* Pr = P + (size_t)(m_base + m_l) * KCD;
            int c8 = lane;
            int k = c8 >> 3, c0 = (c8 & 7) << 3;
            int swz = (k << 6) | (c0 ^ (((k >> 2) & 3) << 4));
            s16x8 v0 = *(const s16x8*)&pbuf[w][swz];
            *(s16x8*)(Pr + c8 * 8) = v0;
            int c8b = 64 + lane;
            if (c8b < 120) {
                int kb = c8b >> 3, c0b = (c8b & 7) << 3;
                int swzb = (kb << 6) | (c0b ^ (((kb >> 2) & 3) << 4));
                s16x8 v1 = *(const s16x8*)&pbuf[w][swzb];
                *(s16x8*)(Pr + c8b * 8) = v1;
            }
        }
    }
}

// ---- SPLIT kernel P2: out(50000x64) = P(50000x960) @ WT^T -------------------
// R12 rewrite: 80 queries/block (grid 625 exact), wave = 16-d tile x 5 m-tiles.
// One WT b-frag load serves 5 MFMAs; (256,4) gives the allocator ~128 VGPRs so
// ~18 16B loads stay in flight (R11's (256,8) -> 24 VGPR was the 90us bug).
__global__ __launch_bounds__(256, 4)
void kpconv_p2(const unsigned short* __restrict__ P,
               const unsigned short* __restrict__ WT,
               float* __restrict__ out) {
    int tid = threadIdx.x, w = tid >> 6, lane = tid & 63;
    int row = lane & 15, quad = lane >> 4, kq = quad << 3;
    int m_base = blockIdx.x * 80;
    int dbase = w << 4;
    const unsigned short* bp = WT + (size_t)(dbase + row) * KCD + kq;
    const unsigned short* ap = P + (size_t)(m_base + row) * KCD + kq;

    f32x4 acc0 = {0.f, 0.f, 0.f, 0.f};
    f32x4 acc1 = {0.f, 0.f, 0.f, 0.f};
    f32x4 acc2 = {0.f, 0.f, 0.f, 0.f};
    f32x4 acc3 = {0.f, 0.f, 0.f, 0.f};
    f32x4 acc4 = {0.f, 0.f, 0.f, 0.f};

    #pragma unroll 3
    for (int s = 0; s < 30; ++s) {
        s16x8 b = *(const s16x8*)(bp + s * 32);
        s16x8 a0 = *(const s16x8*)(ap + (size_t)0 * 16 * KCD + s * 32);
        s16x8 a1 = *(const s16x8*)(ap + (size_t)1 * 16 * KCD + s * 32);
        s16x8 a2 = *(const s16x8*)(ap + (size_t)2 * 16 * KCD + s * 32);
        s16x8 a3 = *(const s16x8*)(ap + (size_t)3 * 16 * KCD + s * 32);
        s16x8 a4 = *(const s16x8*)(ap + (size_t)4 * 16 * KCD + s * 32);
        acc0 = __builtin_amdgcn_mfma_f32_16x16x32_bf16(a0, b, acc0, 0, 0, 0);
        acc1 = __builtin_amdgcn_mfma_f32_16x16x32_bf16(a1, b, acc1, 0, 0, 0);
        acc2 = __builtin_amdgcn_mfma_f32_16x16x32_bf16(a2, b, acc2, 0, 0, 0);
        acc3 = __builtin_amdgcn_mfma_f32_16x16x32_bf16(a3, b, acc3, 0, 0, 0);
        acc4 = __builtin_amdgcn_mfma_f32_16x16x32_bf16(a4, b, acc4, 0, 0, 0);
    }

    #pragma unroll
    for (int r = 0; r < 4; ++r) {
        int mq = quad * 4 + r;
        size_t o0 = (size_t)(m_base + mq) * 64 + dbase + row;
        out[o0 + (size_t)0 * 16 * 64] = acc0[r];
        out[o0 + (size_t)1 * 16 * 64] = acc1[r];
        out[o0 + (size_t)2 * 16 * 64] = acc2[r];
        out[o0 + (size_t)3 * 16 * 64] = acc3[r];
        out[o0 + (size_t)4 * 16 * 64] = acc4[r];
    }
}

// ---- fused fallback (R9, proven) --------------------------------------------
template <bool USE_BF>
__device__ __forceinline__
void kpconv_body(const float* __restrict__ q_points,
                 const float* __restrict__ s_points,
                 const float* __restrict__ s_feats,
                 const unsigned short* __restrict__ fbf,
                 const int* __restrict__ ni,
                 const float* __restrict__ kpts,
                 const unsigned short* __restrict__ WT,
                 const unsigned char* __restrict__ signs,
                 float* __restrict__ out) {
    __shared__ __align__(16) unsigned short P_sh[16][PSTRIDE];
    __shared__ __align__(16) float rpos_sh[4][3][32];
    __shared__ int ni_sh[4][4][32];
    __shared__ float kp_sh[16][3];
    __shared__ float q_sh[16][3];
    __shared__ float inv_nnum[16];

    int tid = threadIdx.x, w = tid >> 6, lane = tid & 63;
    int m_base = blockIdx.x << 4;

    if (tid < 48) {
        kp_sh[tid / 3][tid % 3] = (tid < 45) ? kpts[tid] : 1e9f;
        q_sh[tid / 3][tid % 3] = q_points[m_base * 3 + tid];
    }
    __syncthreads();

    int h = lane & 31;
    int row = lane & 15, quad = lane >> 4, kq = quad << 3;
    int h2 = lane >> 1, half = lane & 1;

    float kx = kp_sh[row][0], ky = kp_sh[row][1], kz = kp_sh[row][2];

    float tkx[8], tky[8], tkz[8];
    #pragma unroll
    for (int j = 0; j < 8; ++j) {
        int k = half * 8 + j;
        tkx[j] = kp_sh[k][0]; tky[j] = kp_sh[k][1]; tkz[j] = kp_sh[k][2];
    }

    int idx4[4]; float rxa[4], rya[4], rza[4]; unsigned char sg4[4];
    #pragma unroll
    for (int mi = 0; mi < 4; ++mi)
        idx4[mi] = ni[(m_base + mi * 4 + w) * HN + h];
    #pragma unroll
    for (int mi = 0; mi < 4; ++mi) {
        int m_l = mi * 4 + w;
        bool valid = idx4[mi] < NPTS;
        const float* sp = s_points + (size_t)(valid ? idx4[mi] : 0) * 3;
        float px = sp[0], py = sp[1], pz = sp[2];
        unsigned char sg = signs[valid ? idx4[mi] : 0];
        rxa[mi] = (valid ? px : 1e6f) - q_sh[m_l][0];
        rya[mi] = (valid ? py : 1e6f) - q_sh[m_l][1];
        rza[mi] = (valid ? pz : 1e6f) - q_sh[m_l][2];
        sg4[mi] = valid ? sg : 0;
    }

    #pragma unroll
    for (int mi = 0; mi < 4; ++mi) {
        float rx2 = __shfl(rxa[mi], h2);
        float ry2 = __shfl(rya[mi], h2);
        float rz2 = __shfl(rza[mi], h2);
        int idx2 = __shfl(idx4[mi], h2);
        int av = 0;
        #pragma unroll
        for (int j = 0; j < 8; ++j) {
            float dx = rx2 - tkx[j], dy = ry2 - tky[j], dz = rz2 - tkz[j];
            float d2 = dx * dx + dy * dy + dz * dz;
            av |= (d2 < 1.f) ? 1 : 0;
        }
        av |= __shfl_xor(av, 1);
        bool alive = (idx2 < NPTS) && (av != 0);
        if (half == 0) ni_sh[w][mi][h2] = alive ? idx2 : NPTS;

        unsigned long long pm = __ballot((lane < 32) && (idx4[mi] < NPTS) && sg4[mi]);
        if (lane == 0) {
            int cnt = __popcll(pm);
            inv_nnum[mi * 4 + w] = 1.f / (float)(cnt < 1 ? 1 : cnt);
        }
    }

    #pragma unroll
    for (int mi = 0; mi < 4; ++mi) {
        int m_l = mi * 4 + w;
        if (lane < 32) {
            rpos_sh[w][0][h] = rxa[mi];
            rpos_sh[w][1][h] = rya[mi];
            rpos_sh[w][2][h] = rza[mi];
        }

        float g0[8], g1[8], g2[8], g3[8];
        unsigned d0[8], d1[8];
        #pragma unroll
        for (int j = 0; j < 8; ++j) {
            int idxj = ni_sh[w][mi][kq + j];
            if (USE_BF) {
                d0[j] = 0u; d1[j] = 0u;
                if (idxj < NPTS) {
                    uint2 v = *(const uint2*)(fbf + (size_t)idxj * 64 + row * 4);
                    d0[j] = v.x; d1[j] = v.y;
                }
            } else {
                g0[j] = 0.f; g1[j] = 0.f; g2[j] = 0.f; g3[j] = 0.f;
                if (idxj < NPTS) {
                    const float* fp = s_feats + (size_t)idxj * 64 + row;
                    g0[j] = fp[0]; g1[j] = fp[16]; g2[j] = fp[32]; g3[j] = fp[48];
                }
            }
        }

        float4 ra0 = *(const float4*)&rpos_sh[w][0][kq];
        float4 ra1 = *(const float4*)&rpos_sh[w][0][kq + 4];
        float4 rb0 = *(const float4*)&rpos_sh[w][1][kq];
        float4 rb1 = *(const float4*)&rpos_sh[w][1][kq + 4];
        float4 rc0 = *(const float4*)&rpos_sh[w][2][kq];
        float4 rc1 = *(const float4*)&rpos_sh[w][2][kq + 4];
        float hx[8] = {ra0.x, ra0.y, ra0.z, ra0.w, ra1.x, ra1.y, ra1.z, ra1.w};
        float hy[8] = {rb0.x, rb0.y, rb0.z, rb0.w, rb1.x, rb1.y, rb1.z, rb1.w};
        float hz[8] = {rc0.x, rc0.y, rc0.z, rc0.w, rc1.x, rc1.y, rc1.z, rc1.w};
        float infl[8];
        #pragma unroll
        for (int j = 0; j < 8; ++j) {
            float dx = hx[j] - kx, dy = hy[j] - ky, dz = hz[j] - kz;
            float d2 = dx * dx + dy * dy + dz * dz;
            float f = 1.f - sqrtf(d2);
            infl[j] = f > 0.f ? f : 0.f;
        }
        union { unsigned u[4]; s16x8 v; } af;
        #pragma unroll
        for (int p = 0; p < 4; ++p) af.u[p] = pack_bf(infl[2 * p], infl[2 * p + 1]);

        #pragma unroll
        for (int ch = 0; ch < 4; ++ch) {
            union { unsigned u[4]; s16x8 v; } bfr;
            if (USE_BF) {
                #pragma unroll
                for (int p = 0; p < 4; ++p) {
                    unsigned a = (ch < 2) ? d0[2 * p] : d1[2 * p];
                    unsigned b = (ch < 2) ? d0[2 * p + 1] : d1[2 * p + 1];
                    bfr.u[p] = (ch & 1) ? pack_hi16(a, b) : pack_lo16(a, b);
                }
            } else {
                const float* gs = (ch == 0) ? g0 : (ch == 1) ? g1 : (ch == 2) ? g2 : g3;
                #pragma unroll
                for (int p = 0; p < 4; ++p) bfr.u[p] = pack_bf(gs[2 * p], gs[2 * p + 1]);
            }
            f32x4 acc = {0.f, 0.f, 0.f, 0.f};
            acc = __builtin_amdgcn_mfma_f32_16x16x32_bf16(af.v, bfr.v, acc, 0, 0, 0);
            int cc = ch * 16 + row;
            #pragma unroll
            for (int r = 0; r < 4; ++r) {
                int k2 = quad * 4 + r;
                if (k2 < 15) {
                    int col = (k2 << 6) | (cc ^ ((k2 >> 2) << 4));
                    P_sh[m_l][col] = bf_trunc(acc[r]);
                }
            }
        }
    }
    __syncthreads();

    {
        int dbase = w << 4;
        f32x4 acc = {0.f, 0.f, 0.f, 0.f};
        const unsigned short* wtp = WT + (size_t)(dbase + row) * KCD + kq;
        #pragma unroll 6
        for (int s = 0; s < 30; ++s) {
            int k = s >> 1;
            int c0 = ((s & 1) << 5) + kq;
            int cx = c0 ^ (((k >> 2) & 3) << 4);
            s16x8 a = *(const s16x8*)&P_sh[row][(k << 6) | cx];
            s16x8 b = *(const s16x8*)&wtp[s * 32];
            acc = __builtin_amdgcn_mfma_f32_16x16x32_bf16(a, b, acc, 0, 0, 0);
        }
        #pragma unroll
        for (int r = 0; r < 4; ++r) {
            int m_l = quad * 4 + r;
            out[(size_t)(m_base + m_l) * 64 + dbase + row] = acc[r] * inv_nnum[m_l];
        }
    }
}

__global__ __launch_bounds__(256, 4)
void kpconv_main_bf(const float* __restrict__ q, const float* __restrict__ sp,
                    const unsigned short* __restrict__ fbf,
                    const int* __restrict__ ni, const float* __restrict__ kp,
                    const unsigned short* __restrict__ WT,
                    const unsigned char* __restrict__ signs,
                    float* __restrict__ out) {
    kpconv_body<true>(q, sp, nullptr, fbf, ni, kp, WT, signs, out);
}

__global__ __launch_bounds__(256, 4)
void kpconv_main_f32(const float* __restrict__ q, const float* __restrict__ sp,
                     const float* __restrict__ sf,
                     const int* __restrict__ ni, const float* __restrict__ kp,
                     const unsigned short* __restrict__ WT,
                     const unsigned char* __restrict__ signs,
                     float* __restrict__ out) {
    kpconv_body<false>(q, sp, sf, nullptr, ni, kp, WT, signs, out);
}

extern "C" void kernel_launch(void* const* d_in, const int* in_sizes, int n_in,
                              void* d_out, int out_size, void* d_ws, size_t ws_size,
                              hipStream_t stream) {
    const float* q  = (const float*)d_in[0];
    const float* sp = (const float*)d_in[1];
    const float* sf = (const float*)d_in[2];
    const int*   ni = (const int*)d_in[3];
    const float* kp = (const float*)d_in[4];
    const float* wt = (const float*)d_in[5];
    float* out = (float*)d_out;

    unsigned short* WT = (unsigned short*)d_ws;                    // 122880 B
    unsigned char* signs = (unsigned char*)d_ws + 122880;          // 50000 B
    const size_t off_fbf = 172928;
    unsigned short* fbf = (unsigned short*)((char*)d_ws + off_fbf); // 6.4 MB
    const size_t off_P = off_fbf + (size_t)NPTS * 64 * 2;           // 6572928
    unsigned short* P = (unsigned short*)((char*)d_ws + off_P);     // 96 MB
    const size_t need_bf = off_P;
    const size_t need_split = off_P + (size_t)MPTS * KCD * 2;

    if (ws_size >= need_split) {
        hipLaunchKernelGGL(prep_bf, dim3(240 + NPTS / 16), dim3(256), 0, stream,
                           wt, sf, WT, signs, fbf);
        hipLaunchKernelGGL(kpconv_p1, dim3(MPTS / 16), dim3(256), 0, stream,
                           q, sp, fbf, ni, kp, signs, P);
        hipLaunchKernelGGL(kpconv_p2, dim3(MPTS / 80), dim3(256), 0, stream,
                           P, WT, out);
    } else if (ws_size >= need_bf) {
        hipLaunchKernelGGL(prep_bf, dim3(240 + NPTS / 16), dim3(256), 0, stream,
                           wt, sf, WT, signs, fbf);
        hipLaunchKernelGGL(kpconv_main_bf, dim3(MPTS / 16), dim3(256), 0, stream,
                           q, sp, fbf, ni, kp, WT, signs, out);
    } else {
        hipLaunchKernelGGL(prep_f32, dim3(240 + NPTS / 16), dim3(256), 0, stream,
                           wt, sf, WT, signs);
        hipLaunchKernelGGL(kpconv_main_f32, dim3(MPTS / 16), dim3(256), 0, stream,
                           q, sp, sf, ni, kp, WT, signs, out);
    }
}

// Round 13
// 167.709 us; speedup vs baseline: 1.2113x; 1.0618x over previous
//
#include <hip/hip_runtime.h>

#define NPTS 50000
#define MPTS 50000
#define HN 32
#define KCD 960      // 15 kernel pts * 64 Cin
#define PSTRIDE 968  // fused-path P_sh stride (R6/R9-proven)

typedef float f32x4 __attribute__((ext_vector_type(4)));
typedef short s16x8 __attribute__((ext_vector_type(8)));

__device__ __forceinline__ unsigned short bf_rne(float x) {
    union { float f; unsigned u; } v; v.f = x;
    unsigned r = v.u + 0x7fffu + ((v.u >> 16) & 1u);
    return (unsigned short)(r >> 16);
}
__device__ __forceinline__ unsigned short bf_trunc(float x) {
    union { float f; unsigned u; } v; v.f = x;
    return (unsigned short)(v.u >> 16);
}
__device__ __forceinline__ unsigned pack_bf(float lo, float hi) {
    union { float f; unsigned u; } a, b; a.f = lo; b.f = hi;
    return __builtin_amdgcn_perm(b.u, a.u, 0x07060302u);
}
__device__ __forceinline__ unsigned pack_rne(float lo, float hi) {
    return ((unsigned)bf_rne(hi) << 16) | (unsigned)bf_rne(lo);
}
__device__ __forceinline__ unsigned pack_lo16(unsigned a, unsigned b) {
    return __builtin_amdgcn_perm(b, a, 0x05040100u);
}
__device__ __forceinline__ unsigned pack_hi16(unsigned a, unsigned b) {
    return __builtin_amdgcn_perm(b, a, 0x07060302u);
}

// ---- prep: WT + fbf + signs + spt4 (pos+signflag fused, 16B aligned) --------
__global__ __launch_bounds__(256) void prep_bf(const float* __restrict__ w,
                                               const float* __restrict__ feats,
                                               const float* __restrict__ s_points,
                                               unsigned short* __restrict__ WT,
                                               unsigned char* __restrict__ signs,
                                               float4* __restrict__ spt4,
                                               unsigned short* __restrict__ fbf) {
    int b = blockIdx.x;
    if (b < 240) {
        int t = b * 256 + threadIdx.x;
        int kc = t >> 6, d = t & 63;
        WT[d * KCD + kc] = bf_rne(w[t]);
    } else {
        int t = threadIdx.x;
        int p = t >> 4, r = t & 15;
        int n = (b - 240) * 16 + p;        // 3125*16 = 50000 exactly
        const float* src = feats + (size_t)n * 64 + r;
        float c0 = src[0], c1 = src[16], c2 = src[32], c3 = src[48];
        float s = c0 + c1 + c2 + c3;
        s += __shfl_xor(s, 1); s += __shfl_xor(s, 2);
        s += __shfl_xor(s, 4); s += __shfl_xor(s, 8);
        if (r == 0) {
            signs[n] = (s > 0.f) ? 1 : 0;
            const float* sp = s_points + (size_t)n * 3;
            spt4[n] = float4{sp[0], sp[1], sp[2], (s > 0.f) ? 1.f : 0.f};
        }
        uint2 o; o.x = pack_rne(c0, c1); o.y = pack_rne(c2, c3);
        *(uint2*)(fbf + (size_t)n * 64 + r * 4) = o;
    }
}

__global__ __launch_bounds__(256) void prep_f32(const float* __restrict__ w,
                                                const float* __restrict__ feats,
                                                unsigned short* __restrict__ WT,
                                                unsigned char* __restrict__ signs) {
    int b = blockIdx.x;
    if (b < 240) {
        int t = b * 256 + threadIdx.x;
        int kc = t >> 6, d = t & 63;
        WT[d * KCD + kc] = bf_rne(w[t]);
    } else {
        int lane = threadIdx.x & 63, wv = threadIdx.x >> 6;
        int r4 = lane >> 4, c16 = lane & 15;
        int n = (b - 240) * 16 + wv * 4 + r4;
        float4 v = *(const float4*)(feats + (size_t)n * 64 + c16 * 4);
        float s = v.x + v.y + v.z + v.w;
        s += __shfl_xor(s, 1); s += __shfl_xor(s, 2);
        s += __shfl_xor(s, 4); s += __shfl_xor(s, 8);
        if (c16 == 0) signs[n] = (s > 0.f) ? 1 : 0;
    }
}

// ---- P1: gather + influence + first MFMA -> P (bf16, XOR-swizzled chunks) ---
__global__ __launch_bounds__(256, 6)
void kpconv_p1(const float* __restrict__ q_points,
               const float4* __restrict__ spt4,
               const unsigned short* __restrict__ fbf,
               const int* __restrict__ ni,
               const float* __restrict__ kpts,
               unsigned short* __restrict__ P) {
    __shared__ __align__(16) unsigned short pbuf[4][1032];
    __shared__ __align__(16) float rpos_sh[4][3][32];
    __shared__ int ni_sh[4][4][32];
    __shared__ float kp_sh[16][3];
    __shared__ float q_sh[16][3];

    int tid = threadIdx.x, w = tid >> 6, lane = tid & 63;
    int m_base = blockIdx.x << 4;

    if (tid < 48) {
        kp_sh[tid / 3][tid % 3] = (tid < 45) ? kpts[tid] : 1e9f;
        q_sh[tid / 3][tid % 3] = q_points[m_base * 3 + tid];
    }
    __syncthreads();

    int h = lane & 31;
    int row = lane & 15, quad = lane >> 4, kq = quad << 3;
    int h2 = lane >> 1, half = lane & 1;

    float kx = kp_sh[row][0], ky = kp_sh[row][1], kz = kp_sh[row][2];

    float tkx[8], tky[8], tkz[8];
    #pragma unroll
    for (int j = 0; j < 8; ++j) {
        int k = half * 8 + j;
        tkx[j] = kp_sh[k][0]; tky[j] = kp_sh[k][1]; tkz[j] = kp_sh[k][2];
    }

    int idx4[4]; float rxa[4], rya[4], rza[4]; unsigned char sg4[4];
    #pragma unroll
    for (int mi = 0; mi < 4; ++mi)
        idx4[mi] = ni[(m_base + mi * 4 + w) * HN + h];
    #pragma unroll
    for (int mi = 0; mi < 4; ++mi) {
        int m_l = mi * 4 + w;
        bool valid = idx4[mi] < NPTS;
        float4 pv = spt4[valid ? idx4[mi] : 0];   // pos + sign in one 16B gather
        rxa[mi] = (valid ? pv.x : 1e6f) - q_sh[m_l][0];
        rya[mi] = (valid ? pv.y : 1e6f) - q_sh[m_l][1];
        rza[mi] = (valid ? pv.z : 1e6f) - q_sh[m_l][2];
        sg4[mi] = (valid && pv.w != 0.f) ? 1 : 0;
    }

    float inv4[4];
    #pragma unroll
    for (int mi = 0; mi < 4; ++mi) {
        float rx2 = __shfl(rxa[mi], h2);
        float ry2 = __shfl(rya[mi], h2);
        float rz2 = __shfl(rza[mi], h2);
        int idx2 = __shfl(idx4[mi], h2);
        int av = 0;
        #pragma unroll
        for (int j = 0; j < 8; ++j) {
            float dx = rx2 - tkx[j], dy = ry2 - tky[j], dz = rz2 - tkz[j];
            float d2 = dx * dx + dy * dy + dz * dz;
            av |= (d2 < 1.f) ? 1 : 0;
        }
        av |= __shfl_xor(av, 1);
        bool alive = (idx2 < NPTS) && (av != 0);
        if (half == 0) ni_sh[w][mi][h2] = alive ? idx2 : NPTS;

        unsigned long long pm = __ballot((lane < 32) && sg4[mi]);
        int cnt = __popcll(pm);
        inv4[mi] = 1.f / (float)(cnt < 1 ? 1 : cnt);
    }

    #pragma unroll
    for (int mi = 0; mi < 4; ++mi) {
        int m_l = mi * 4 + w;
        if (lane < 32) {
            rpos_sh[w][0][h] = rxa[mi];
            rpos_sh[w][1][h] = rya[mi];
            rpos_sh[w][2][h] = rza[mi];
        }

        unsigned d0[8], d1[8];
        #pragma unroll
        for (int j = 0; j < 8; ++j) {
            int idxj = ni_sh[w][mi][kq + j];
            d0[j] = 0u; d1[j] = 0u;
            if (idxj < NPTS) {
                uint2 v = *(const uint2*)(fbf + (size_t)idxj * 64 + row * 4);
                d0[j] = v.x; d1[j] = v.y;
            }
        }

        float4 ra0 = *(const float4*)&rpos_sh[w][0][kq];
        float4 ra1 = *(const float4*)&rpos_sh[w][0][kq + 4];
        float4 rb0 = *(const float4*)&rpos_sh[w][1][kq];
        float4 rb1 = *(const float4*)&rpos_sh[w][1][kq + 4];
        float4 rc0 = *(const float4*)&rpos_sh[w][2][kq];
        float4 rc1 = *(const float4*)&rpos_sh[w][2][kq + 4];
        float hx[8] = {ra0.x, ra0.y, ra0.z, ra0.w, ra1.x, ra1.y, ra1.z, ra1.w};
        float hy[8] = {rb0.x, rb0.y, rb0.z, rb0.w, rb1.x, rb1.y, rb1.z, rb1.w};
        float hz[8] = {rc0.x, rc0.y, rc0.z, rc0.w, rc1.x, rc1.y, rc1.z, rc1.w};
        float infl[8];
        #pragma unroll
        for (int j = 0; j < 8; ++j) {
            float dx = hx[j] - kx, dy = hy[j] - ky, dz = hz[j] - kz;
            float d2 = dx * dx + dy * dy + dz * dz;
            float f = 1.f - sqrtf(d2);
            infl[j] = f > 0.f ? f : 0.f;
        }
        union { unsigned u[4]; s16x8 v; } af;
        #pragma unroll
        for (int p = 0; p < 4; ++p) af.u[p] = pack_bf(infl[2 * p], infl[2 * p + 1]);

        #pragma unroll
        for (int ch = 0; ch < 4; ++ch) {
            union { unsigned u[4]; s16x8 v; } bfr;
            #pragma unroll
            for (int p = 0; p < 4; ++p) {
                unsigned a = (ch < 2) ? d0[2 * p] : d1[2 * p];
                unsigned b = (ch < 2) ? d0[2 * p + 1] : d1[2 * p + 1];
                bfr.u[p] = (ch & 1) ? pack_hi16(a, b) : pack_lo16(a, b);
            }
            f32x4 acc = {0.f, 0.f, 0.f, 0.f};
            acc = __builtin_amdgcn_mfma_f32_16x16x32_bf16(af.v, bfr.v, acc, 0, 0, 0);
            int cc = ch * 16 + row;
            #pragma unroll
            for (int r = 0; r < 4; ++r) {
                int k2 = quad * 4 + r;
                int col = (k2 << 6) | (cc ^ ((k2 >> 2) << 4));
                pbuf[w][col] = bf_trunc(acc[r] * inv4[mi]);
            }
        }

        // flush query's 1920B, chunk-XOR-swizzled by (m&7) so P2's LDS image is
        // bank-conflict-free (row stride 1920B = 0 mod 128B otherwise).
        {
            unsigned short* Pr = P + (size_t)(m_base + m_l) * KCD;
            int sw = m_l & 7;
            int c8 = lane;                       // chunks of 8 shorts
            int k = c8 >> 3, c0 = (c8 & 7) << 3;
            int swz = (k << 6) | (c0 ^ (((k >> 2) & 3) << 4));
            s16x8 v0 = *(const s16x8*)&pbuf[w][swz];
            *(s16x8*)(Pr + (c8 ^ sw) * 8) = v0;
            int c8b = 64 + lane;
            if (c8b < 120) {
                int kb = c8b >> 3, c0b = (c8b & 7) << 3;
                int swzb = (kb << 6) | (c0b ^ (((kb >> 2) & 3) << 4));
                s16x8 v1 = *(const s16x8*)&pbuf[w][swzb];
                *(s16x8*)(Pr + (c8b ^ sw) * 8) = v1;
            }
        }
    }
}

// ---- P2: out = P @ WT^T with LDS-staged A (the anti-serialization fix) ------
// 16 q/block, grid 3125. A-tile (30720B contiguous) bulk-copied to LDS, then
// 30 x { ds_read_b128 A + L2-hot WT load + MFMA } per wave. XOR swizzle makes
// the ds_reads 2-way max (free). LDS 30720 -> 5 blocks/CU, ~20 waves/CU TLP.
__global__ __launch_bounds__(256, 4)
void kpconv_p2(const unsigned short* __restrict__ P,
               const unsigned short* __restrict__ WT,
               float* __restrict__ out) {
    __shared__ __align__(16) unsigned short A_lds[16 * KCD];  // 30720 B
    int tid = threadIdx.x, w = tid >> 6, lane = tid & 63;
    int row = lane & 15, quad = lane >> 4, kq = quad << 3;
    int m_base = blockIdx.x << 4;

    {   // bulk stage: 1920 uint4s = 7 full rounds + half round
        const uint4* src = (const uint4*)(P + (size_t)m_base * KCD);
        uint4* dst = (uint4*)A_lds;
        uint4 t0 = src[tid];
        uint4 t1 = src[tid + 256];
        uint4 t2 = src[tid + 512];
        uint4 t3 = src[tid + 768];
        uint4 t4 = src[tid + 1024];
        uint4 t5 = src[tid + 1280];
        uint4 t6 = src[tid + 1536];
        dst[tid] = t0;
        dst[tid + 256] = t1;
        dst[tid + 512] = t2;
        dst[tid + 768] = t3;
        dst[tid + 1024] = t4;
        dst[tid + 1280] = t5;
        dst[tid + 1536] = t6;
        if (tid < 128) dst[tid + 1792] = src[tid + 1792];
    }
    __syncthreads();

    int dbase = w << 4;
    const unsigned short* bp = WT + (size_t)(dbase + row) * KCD + kq;
    const unsigned short* arow = A_lds + row * KCD;
    int sw = row & 7;
    f32x4 acc = {0.f, 0.f, 0.f, 0.f};
    #pragma unroll
    for (int s = 0; s < 30; ++s) {
        int c8 = (s * 4 + quad) ^ sw;
        s16x8 a = *(const s16x8*)(arow + c8 * 8);
        s16x8 b = *(const s16x8*)(bp + s * 32);
        acc = __builtin_amdgcn_mfma_f32_16x16x32_bf16(a, b, acc, 0, 0, 0);
    }
    #pragma unroll
    for (int r = 0; r < 4; ++r) {
        int m_l = quad * 4 + r;
        out[(size_t)(m_base + m_l) * 64 + dbase + row] = acc[r];
    }
}

// ---- fused fallback (R9, proven 150.4 us) -----------------------------------
template <bool USE_BF>
__device__ __forceinline__
void kpconv_body(const float* __restrict__ q_points,
                 const float* __restrict__ s_points,
                 const float* __restrict__ s_feats,
                 const unsigned short* __restrict__ fbf,
                 const int* __restrict__ ni,
                 const float* __restrict__ kpts,
                 const unsigned short* __restrict__ WT,
                 const unsigned char* __restrict__ signs,
                 float* __restrict__ out) {
    __shared__ __align__(16) unsigned short P_sh[16][PSTRIDE];
    __shared__ __align__(16) float rpos_sh[4][3][32];
    __shared__ int ni_sh[4][4][32];
    __shared__ float kp_sh[16][3];
    __shared__ float q_sh[16][3];
    __shared__ float inv_nnum[16];

    int tid = threadIdx.x, w = tid >> 6, lane = tid & 63;
    int m_base = blockIdx.x << 4;

    if (tid < 48) {
        kp_sh[tid / 3][tid % 3] = (tid < 45) ? kpts[tid] : 1e9f;
        q_sh[tid / 3][tid % 3] = q_points[m_base * 3 + tid];
    }
    __syncthreads();

    int h = lane & 31;
    int row = lane & 15, quad = lane >> 4, kq = quad << 3;
    int h2 = lane >> 1, half = lane & 1;

    float kx = kp_sh[row][0], ky = kp_sh[row][1], kz = kp_sh[row][2];

    float tkx[8], tky[8], tkz[8];
    #pragma unroll
    for (int j = 0; j < 8; ++j) {
        int k = half * 8 + j;
        tkx[j] = kp_sh[k][0]; tky[j] = kp_sh[k][1]; tkz[j] = kp_sh[k][2];
    }

    int idx4[4]; float rxa[4], rya[4], rza[4]; unsigned char sg4[4];
    #pragma unroll
    for (int mi = 0; mi < 4; ++mi)
        idx4[mi] = ni[(m_base + mi * 4 + w) * HN + h];
    #pragma unroll
    for (int mi = 0; mi < 4; ++mi) {
        int m_l = mi * 4 + w;
        bool valid = idx4[mi] < NPTS;
        const float* sp = s_points + (size_t)(valid ? idx4[mi] : 0) * 3;
        float px = sp[0], py = sp[1], pz = sp[2];
        unsigned char sg = signs[valid ? idx4[mi] : 0];
        rxa[mi] = (valid ? px : 1e6f) - q_sh[m_l][0];
        rya[mi] = (valid ? py : 1e6f) - q_sh[m_l][1];
        rza[mi] = (valid ? pz : 1e6f) - q_sh[m_l][2];
        sg4[mi] = valid ? sg : 0;
    }

    #pragma unroll
    for (int mi = 0; mi < 4; ++mi) {
        float rx2 = __shfl(rxa[mi], h2);
        float ry2 = __shfl(rya[mi], h2);
        float rz2 = __shfl(rza[mi], h2);
        int idx2 = __shfl(idx4[mi], h2);
        int av = 0;
        #pragma unroll
        for (int j = 0; j < 8; ++j) {
            float dx = rx2 - tkx[j], dy = ry2 - tky[j], dz = rz2 - tkz[j];
            float d2 = dx * dx + dy * dy + dz * dz;
            av |= (d2 < 1.f) ? 1 : 0;
        }
        av |= __shfl_xor(av, 1);
        bool alive = (idx2 < NPTS) && (av != 0);
        if (half == 0) ni_sh[w][mi][h2] = alive ? idx2 : NPTS;

        unsigned long long pm = __ballot((lane < 32) && (idx4[mi] < NPTS) && sg4[mi]);
        if (lane == 0) {
            int cnt = __popcll(pm);
            inv_nnum[mi * 4 + w] = 1.f / (float)(cnt < 1 ? 1 : cnt);
        }
    }

    #pragma unroll
    for (int mi = 0; mi < 4; ++mi) {
        int m_l = mi * 4 + w;
        if (lane < 32) {
            rpos_sh[w][0][h] = rxa[mi];
            rpos_sh[w][1][h] = rya[mi];
            rpos_sh[w][2][h] = rza[mi];
        }

        float g0[8], g1[8], g2[8], g3[8];
        unsigned d0[8], d1[8];
        #pragma unroll
        for (int j = 0; j < 8; ++j) {
            int idxj = ni_sh[w][mi][kq + j];
            if (USE_BF) {
                d0[j] = 0u; d1[j] = 0u;
                if (idxj < NPTS) {
                    uint2 v = *(const uint2*)(fbf + (size_t)idxj * 64 + row * 4);
                    d0[j] = v.x; d1[j] = v.y;
                }
            } else {
                g0[j] = 0.f; g1[j] = 0.f; g2[j] = 0.f; g3[j] = 0.f;
                if (idxj < NPTS) {
                    const float* fp = s_feats + (size_t)idxj * 64 + row;
                    g0[j] = fp[0]; g1[j] = fp[16]; g2[j] = fp[32]; g3[j] = fp[48];
                }
            }
        }

        float4 ra0 = *(const float4*)&rpos_sh[w][0][kq];
        float4 ra1 = *(const float4*)&rpos_sh[w][0][kq + 4];
        float4 rb0 = *(const float4*)&rpos_sh[w][1][kq];
        float4 rb1 = *(const float4*)&rpos_sh[w][1][kq + 4];
        float4 rc0 = *(const float4*)&rpos_sh[w][2][kq];
        float4 rc1 = *(const float4*)&rpos_sh[w][2][kq + 4];
        float hx[8] = {ra0.x, ra0.y, ra0.z, ra0.w, ra1.x, ra1.y, ra1.z, ra1.w};
        float hy[8] = {rb0.x, rb0.y, rb0.z, rb0.w, rb1.x, rb1.y, rb1.z, rb1.w};
        float hz[8] = {rc0.x, rc0.y, rc0.z, rc0.w, rc1.x, rc1.y, rc1.z, rc1.w};
        float infl[8];
        #pragma unroll
        for (int j = 0; j < 8; ++j) {
            float dx = hx[j] - kx, dy = hy[j] - ky, dz = hz[j] - kz;
            float d2 = dx * dx + dy * dy + dz * dz;
            float f = 1.f - sqrtf(d2);
            infl[j] = f > 0.f ? f : 0.f;
        }
        union { unsigned u[4]; s16x8 v; } af;
        #pragma unroll
        for (int p = 0; p < 4; ++p) af.u[p] = pack_bf(infl[2 * p], infl[2 * p + 1]);

        #pragma unroll
        for (int ch = 0; ch < 4; ++ch) {
            union { unsigned u[4]; s16x8 v; } bfr;
            if (USE_BF) {
                #pragma unroll
                for (int p = 0; p < 4; ++p) {
                    unsigned a = (ch < 2) ? d0[2 * p] : d1[2 * p];
                    unsigned b = (ch < 2) ? d0[2 * p + 1] : d1[2 * p + 1];
                    bfr.u[p] = (ch & 1) ? pack_hi16(a, b) : pack_lo16(a, b);
                }
            } else {
                const float* gs = (ch == 0) ? g0 : (ch == 1) ? g1 : (ch == 2) ? g2 : g3;
                #pragma unroll
                for (int p = 0; p < 4; ++p) bfr.u[p] = pack_bf(gs[2 * p], gs[2 * p + 1]);
            }
            f32x4 acc = {0.f, 0.f, 0.f, 0.f};
            acc = __builtin_amdgcn_mfma_f32_16x16x32_bf16(af.v, bfr.v, acc, 0, 0, 0);
            int cc = ch * 16 + row;
            #pragma unroll
            for (int r = 0; r < 4; ++r) {
                int k2 = quad * 4 + r;
                if (k2 < 15) {
                    int col = (k2 << 6) | (cc ^ ((k2 >> 2) << 4));
                    P_sh[m_l][col] = bf_trunc(acc[r]);
                }
            }
        }
    }
    __syncthreads();

    {
        int dbase = w << 4;
        f32x4 acc = {0.f, 0.f, 0.f, 0.f};
        const unsigned short* wtp = WT + (size_t)(dbase + row) * KCD + kq;
        #pragma unroll 6
        for (int s = 0; s < 30; ++s) {
            int k = s >> 1;
            int c0 = ((s & 1) << 5) + kq;
            int cx = c0 ^ (((k >> 2) & 3) << 4);
            s16x8 a = *(const s16x8*)&P_sh[row][(k << 6) | cx];
            s16x8 b = *(const s16x8*)&wtp[s * 32];
            acc = __builtin_amdgcn_mfma_f32_16x16x32_bf16(a, b, acc, 0, 0, 0);
        }
        #pragma unroll
        for (int r = 0; r < 4; ++r) {
            int m_l = quad * 4 + r;
            out[(size_t)(m_base + m_l) * 64 + dbase + row] = acc[r] * inv_nnum[m_l];
        }
    }
}

__global__ __launch_bounds__(256, 4)
void kpconv_main_bf(const float* __restrict__ q, const float* __restrict__ sp,
                    const unsigned short* __restrict__ fbf,
                    const int* __restrict__ ni, const float* __restrict__ kp,
                    const unsigned short* __restrict__ WT,
                    const unsigned char* __restrict__ signs,
                    float* __restrict__ out) {
    kpconv_body<true>(q, sp, nullptr, fbf, ni, kp, WT, signs, out);
}

__global__ __launch_bounds__(256, 4)
void kpconv_main_f32(const float* __restrict__ q, const float* __restrict__ sp,
                     const float* __restrict__ sf,
                     const int* __restrict__ ni, const float* __restrict__ kp,
                     const unsigned short* __restrict__ WT,
                     const unsigned char* __restrict__ signs,
                     float* __restrict__ out) {
    kpconv_body<false>(q, sp, sf, nullptr, ni, kp, WT, signs, out);
}

extern "C" void kernel_launch(void* const* d_in, const int* in_sizes, int n_in,
                              void* d_out, int out_size, void* d_ws, size_t ws_size,
                              hipStream_t stream) {
    const float* q  = (const float*)d_in[0];
    const float* sp = (const float*)d_in[1];
    const float* sf = (const float*)d_in[2];
    const int*   ni = (const int*)d_in[3];
    const float* kp = (const float*)d_in[4];
    const float* wt = (const float*)d_in[5];
    float* out = (float*)d_out;

    unsigned short* WT = (unsigned short*)d_ws;                     // 122880 B
    unsigned char* signs = (unsigned char*)d_ws + 122880;           // 50000 B
    const size_t off_spt = 172928;                                  // 16B aligned
    float4* spt4 = (float4*)((char*)d_ws + off_spt);                // 800000 B
    const size_t off_fbf = off_spt + (size_t)NPTS * 16;             // 972928
    unsigned short* fbf = (unsigned short*)((char*)d_ws + off_fbf); // 6.4 MB
    const size_t off_P = off_fbf + (size_t)NPTS * 64 * 2;           // 7372928
    unsigned short* P = (unsigned short*)((char*)d_ws + off_P);     // 96 MB
    const size_t need_bf = off_P;
    const size_t need_split = off_P + (size_t)MPTS * KCD * 2;

    if (ws_size >= need_split) {
        hipLaunchKernelGGL(prep_bf, dim3(240 + NPTS / 16), dim3(256), 0, stream,
                           wt, sf, sp, WT, signs, spt4, fbf);
        hipLaunchKernelGGL(kpconv_p1, dim3(MPTS / 16), dim3(256), 0, stream,
                           q, spt4, fbf, ni, kp, P);
        hipLaunchKernelGGL(kpconv_p2, dim3(MPTS / 16), dim3(256), 0, stream,
                           P, WT, out);
    } else if (ws_size >= need_bf) {
        hipLaunchKernelGGL(prep_bf, dim3(240 + NPTS / 16), dim3(256), 0, stream,
                           wt, sf, sp, WT, signs, spt4, fbf);
        hipLaunchKernelGGL(kpconv_main_bf, dim3(MPTS / 16), dim3(256), 0, stream,
                           q, sp, fbf, ni, kp, WT, signs, out);
    } else {
        hipLaunchKernelGGL(prep_f32, dim3(240 + NPTS / 16), dim3(256), 0, stream,
                           wt, sf, WT, signs);
        hipLaunchKernelGGL(kpconv_main_f32, dim3(MPTS / 16), dim3(256), 0, stream,
                           q, sp, sf, ni, kp, WT, signs, out);
    }
}

// Round 14
// 136.407 us; speedup vs baseline: 1.4893x; 1.2295x over previous
//
#include <hip/hip_runtime.h>

#define NPTS 50000
#define MPTS 50000
#define HN 32
#define KCD 960      // 15 kernel pts * 64 Cin
#define PSTRIDE 968  // fused-path P_sh stride
#define MPAD 50016   // P rows padded to multiple of 32 for P2's tiles
#define LSTR 200     // P2 LDS row stride in shorts (192 + 8 pad)

typedef float f32x4 __attribute__((ext_vector_type(4)));
typedef short s16x8 __attribute__((ext_vector_type(8)));

__device__ __forceinline__ unsigned short bf_rne(float x) {
    union { float f; unsigned u; } v; v.f = x;
    unsigned r = v.u + 0x7fffu + ((v.u >> 16) & 1u);
    return (unsigned short)(r >> 16);
}
__device__ __forceinline__ unsigned short bf_trunc(float x) {
    union { float f; unsigned u; } v; v.f = x;
    return (unsigned short)(v.u >> 16);
}
__device__ __forceinline__ unsigned pack_bf(float lo, float hi) {
    union { float f; unsigned u; } a, b; a.f = lo; b.f = hi;
    return __builtin_amdgcn_perm(b.u, a.u, 0x07060302u);
}
__device__ __forceinline__ unsigned pack_rne(float lo, float hi) {
    return ((unsigned)bf_rne(hi) << 16) | (unsigned)bf_rne(lo);
}
__device__ __forceinline__ unsigned pack_lo16(unsigned a, unsigned b) {
    return __builtin_amdgcn_perm(b, a, 0x05040100u);
}
__device__ __forceinline__ unsigned pack_hi16(unsigned a, unsigned b) {
    return __builtin_amdgcn_perm(b, a, 0x07060302u);
}

// ---- prep: WT + fbf + signs + spt4 ------------------------------------------
__global__ __launch_bounds__(256) void prep_bf(const float* __restrict__ w,
                                               const float* __restrict__ feats,
                                               const float* __restrict__ s_points,
                                               unsigned short* __restrict__ WT,
                                               unsigned char* __restrict__ signs,
                                               float4* __restrict__ spt4,
                                               unsigned short* __restrict__ fbf) {
    int b = blockIdx.x;
    if (b < 240) {
        int t = b * 256 + threadIdx.x;
        int kc = t >> 6, d = t & 63;
        WT[d * KCD + kc] = bf_rne(w[t]);
    } else {
        int t = threadIdx.x;
        int p = t >> 4, r = t & 15;
        int n = (b - 240) * 16 + p;
        const float* src = feats + (size_t)n * 64 + r;
        float c0 = src[0], c1 = src[16], c2 = src[32], c3 = src[48];
        float s = c0 + c1 + c2 + c3;
        s += __shfl_xor(s, 1); s += __shfl_xor(s, 2);
        s += __shfl_xor(s, 4); s += __shfl_xor(s, 8);
        if (r == 0) {
            signs[n] = (s > 0.f) ? 1 : 0;
            const float* sp = s_points + (size_t)n * 3;
            spt4[n] = float4{sp[0], sp[1], sp[2], (s > 0.f) ? 1.f : 0.f};
        }
        uint2 o; o.x = pack_rne(c0, c1); o.y = pack_rne(c2, c3);
        *(uint2*)(fbf + (size_t)n * 64 + r * 4) = o;
    }
}

__global__ __launch_bounds__(256) void prep_f32(const float* __restrict__ w,
                                                const float* __restrict__ feats,
                                                unsigned short* __restrict__ WT,
                                                unsigned char* __restrict__ signs) {
    int b = blockIdx.x;
    if (b < 240) {
        int t = b * 256 + threadIdx.x;
        int kc = t >> 6, d = t & 63;
        WT[d * KCD + kc] = bf_rne(w[t]);
    } else {
        int lane = threadIdx.x & 63, wv = threadIdx.x >> 6;
        int r4 = lane >> 4, c16 = lane & 15;
        int n = (b - 240) * 16 + wv * 4 + r4;
        float4 v = *(const float4*)(feats + (size_t)n * 64 + c16 * 4);
        float s = v.x + v.y + v.z + v.w;
        s += __shfl_xor(s, 1); s += __shfl_xor(s, 2);
        s += __shfl_xor(s, 4); s += __shfl_xor(s, 8);
        if (c16 == 0) signs[n] = (s > 0.f) ? 1 : 0;
    }
}

// ---- P1: gather + influence + first MFMA -> P (plain row-major bf16) --------
__global__ __launch_bounds__(256, 6)
void kpconv_p1(const float* __restrict__ q_points,
               const float4* __restrict__ spt4,
               const unsigned short* __restrict__ fbf,
               const int* __restrict__ ni,
               const float* __restrict__ kpts,
               unsigned short* __restrict__ P) {
    __shared__ __align__(16) unsigned short pbuf[4][1032];
    __shared__ __align__(16) float rpos_sh[4][3][32];
    __shared__ int ni_sh[4][4][32];
    __shared__ float kp_sh[16][3];
    __shared__ float q_sh[16][3];

    int tid = threadIdx.x, w = tid >> 6, lane = tid & 63;
    int m_base = blockIdx.x << 4;

    if (tid < 48) {
        kp_sh[tid / 3][tid % 3] = (tid < 45) ? kpts[tid] : 1e9f;
        q_sh[tid / 3][tid % 3] = q_points[m_base * 3 + tid];
    }
    __syncthreads();

    int h = lane & 31;
    int row = lane & 15, quad = lane >> 4, kq = quad << 3;
    int h2 = lane >> 1, half = lane & 1;

    float kx = kp_sh[row][0], ky = kp_sh[row][1], kz = kp_sh[row][2];

    float tkx[8], tky[8], tkz[8];
    #pragma unroll
    for (int j = 0; j < 8; ++j) {
        int k = half * 8 + j;
        tkx[j] = kp_sh[k][0]; tky[j] = kp_sh[k][1]; tkz[j] = kp_sh[k][2];
    }

    int idx4[4]; float rxa[4], rya[4], rza[4]; unsigned char sg4[4];
    #pragma unroll
    for (int mi = 0; mi < 4; ++mi)
        idx4[mi] = ni[(m_base + mi * 4 + w) * HN + h];
    #pragma unroll
    for (int mi = 0; mi < 4; ++mi) {
        int m_l = mi * 4 + w;
        bool valid = idx4[mi] < NPTS;
        float4 pv = spt4[valid ? idx4[mi] : 0];
        rxa[mi] = (valid ? pv.x : 1e6f) - q_sh[m_l][0];
        rya[mi] = (valid ? pv.y : 1e6f) - q_sh[m_l][1];
        rza[mi] = (valid ? pv.z : 1e6f) - q_sh[m_l][2];
        sg4[mi] = (valid && pv.w != 0.f) ? 1 : 0;
    }

    float inv4[4];
    #pragma unroll
    for (int mi = 0; mi < 4; ++mi) {
        float rx2 = __shfl(rxa[mi], h2);
        float ry2 = __shfl(rya[mi], h2);
        float rz2 = __shfl(rza[mi], h2);
        int idx2 = __shfl(idx4[mi], h2);
        int av = 0;
        #pragma unroll
        for (int j = 0; j < 8; ++j) {
            float dx = rx2 - tkx[j], dy = ry2 - tky[j], dz = rz2 - tkz[j];
            float d2 = dx * dx + dy * dy + dz * dz;
            av |= (d2 < 1.f) ? 1 : 0;
        }
        av |= __shfl_xor(av, 1);
        bool alive = (idx2 < NPTS) && (av != 0);
        if (half == 0) ni_sh[w][mi][h2] = alive ? idx2 : NPTS;

        unsigned long long pm = __ballot((lane < 32) && sg4[mi]);
        int cnt = __popcll(pm);
        inv4[mi] = 1.f / (float)(cnt < 1 ? 1 : cnt);
    }

    #pragma unroll
    for (int mi = 0; mi < 4; ++mi) {
        int m_l = mi * 4 + w;
        if (lane < 32) {
            rpos_sh[w][0][h] = rxa[mi];
            rpos_sh[w][1][h] = rya[mi];
            rpos_sh[w][2][h] = rza[mi];
        }

        unsigned d0[8], d1[8];
        #pragma unroll
        for (int j = 0; j < 8; ++j) {
            int idxj = ni_sh[w][mi][kq + j];
            d0[j] = 0u; d1[j] = 0u;
            if (idxj < NPTS) {
                uint2 v = *(const uint2*)(fbf + (size_t)idxj * 64 + row * 4);
                d0[j] = v.x; d1[j] = v.y;
            }
        }

        float4 ra0 = *(const float4*)&rpos_sh[w][0][kq];
        float4 ra1 = *(const float4*)&rpos_sh[w][0][kq + 4];
        float4 rb0 = *(const float4*)&rpos_sh[w][1][kq];
        float4 rb1 = *(const float4*)&rpos_sh[w][1][kq + 4];
        float4 rc0 = *(const float4*)&rpos_sh[w][2][kq];
        float4 rc1 = *(const float4*)&rpos_sh[w][2][kq + 4];
        float hx[8] = {ra0.x, ra0.y, ra0.z, ra0.w, ra1.x, ra1.y, ra1.z, ra1.w};
        float hy[8] = {rb0.x, rb0.y, rb0.z, rb0.w, rb1.x, rb1.y, rb1.z, rb1.w};
        float hz[8] = {rc0.x, rc0.y, rc0.z, rc0.w, rc1.x, rc1.y, rc1.z, rc1.w};
        float infl[8];
        #pragma unroll
        for (int j = 0; j < 8; ++j) {
            float dx = hx[j] - kx, dy = hy[j] - ky, dz = hz[j] - kz;
            float d2 = dx * dx + dy * dy + dz * dz;
            float f = 1.f - sqrtf(d2);
            infl[j] = f > 0.f ? f : 0.f;
        }
        union { unsigned u[4]; s16x8 v; } af;
        #pragma unroll
        for (int p = 0; p < 4; ++p) af.u[p] = pack_bf(infl[2 * p], infl[2 * p + 1]);

        #pragma unroll
        for (int ch = 0; ch < 4; ++ch) {
            union { unsigned u[4]; s16x8 v; } bfr;
            #pragma unroll
            for (int p = 0; p < 4; ++p) {
                unsigned a = (ch < 2) ? d0[2 * p] : d1[2 * p];
                unsigned b = (ch < 2) ? d0[2 * p + 1] : d1[2 * p + 1];
                bfr.u[p] = (ch & 1) ? pack_hi16(a, b) : pack_lo16(a, b);
            }
            f32x4 acc = {0.f, 0.f, 0.f, 0.f};
            acc = __builtin_amdgcn_mfma_f32_16x16x32_bf16(af.v, bfr.v, acc, 0, 0, 0);
            int cc = ch * 16 + row;
            #pragma unroll
            for (int r = 0; r < 4; ++r) {
                int k2 = quad * 4 + r;
                int col = (k2 << 6) | (cc ^ ((k2 >> 2) << 4));
                pbuf[w][col] = bf_trunc(acc[r] * inv4[mi]);
            }
        }

        // flush query's 1920B, plain row-major (P2 handles banks via padding)
        {
            unsigned short* Pr = P + (size_t)(m_base + m_l) * KCD;
            int c8 = lane;
            int k = c8 >> 3, c0 = (c8 & 7) << 3;
            int swz = (k << 6) | (c0 ^ (((k >> 2) & 3) << 4));
            s16x8 v0 = *(const s16x8*)&pbuf[w][swz];
            *(s16x8*)(Pr + c8 * 8) = v0;
            int c8b = 64 + lane;
            if (c8b < 120) {
                int kb = c8b >> 3, c0b = (c8b & 7) << 3;
                int swzb = (kb << 6) | (c0b ^ (((kb >> 2) & 3) << 4));
                s16x8 v1 = *(const s16x8*)&pbuf[w][swzb];
                *(s16x8*)(Pr + c8b * 8) = v1;
            }
        }
    }
}

// ---- P2: m97-style GEMM. Block = 32m x 64d, K chunked 5x192, both operands
// staged through padded LDS. All VMEM is bulk streaming; no chained loads.
__global__ __launch_bounds__(256, 4)
void kpconv_p2(const unsigned short* __restrict__ P,
               const unsigned short* __restrict__ WT,
               float* __restrict__ out) {
    __shared__ __align__(16) unsigned short A_lds[32 * LSTR];  // 12800 B
    __shared__ __align__(16) unsigned short B_lds[64 * LSTR];  // 25600 B
    // total 38400 B -> 4 blocks/CU

    int tid = threadIdx.x, w = tid >> 6, lane = tid & 63;
    int row = lane & 15, quad = lane >> 4, kq = quad << 3;
    int m_base = blockIdx.x * 32;

    f32x4 acc0 = {0.f, 0.f, 0.f, 0.f};   // m-rows row
    f32x4 acc1 = {0.f, 0.f, 0.f, 0.f};   // m-rows 16+row

    const unsigned short* Ab = P + (size_t)m_base * KCD;

    for (int kc = 0; kc < 5; ++kc) {
        __syncthreads();   // protect LDS from prior chunk's readers
        // stage A chunk: 32 rows x 24 uint4 = 768; 3 rounds of 256
        uint4 av[3]; int am[3], as[3];
        #pragma unroll
        for (int i = 0; i < 3; ++i) {
            int idx = i * 256 + tid;
            am[i] = idx / 24; as[i] = idx - am[i] * 24;
            av[i] = *(const uint4*)(Ab + (size_t)am[i] * KCD + kc * 192 + as[i] * 8);
        }
        // stage B chunk: 64 rows x 24 uint4 = 1536; 6 rounds
        uint4 bv[6]; int bd[6], bs[6];
        #pragma unroll
        for (int i = 0; i < 6; ++i) {
            int idx = i * 256 + tid;
            bd[i] = idx / 24; bs[i] = idx - bd[i] * 24;
            bv[i] = *(const uint4*)(WT + (size_t)bd[i] * KCD + kc * 192 + bs[i] * 8);
        }
        #pragma unroll
        for (int i = 0; i < 3; ++i)
            *(uint4*)(A_lds + am[i] * LSTR + as[i] * 8) = av[i];
        #pragma unroll
        for (int i = 0; i < 6; ++i)
            *(uint4*)(B_lds + bd[i] * LSTR + bs[i] * 8) = bv[i];
        __syncthreads();

        #pragma unroll
        for (int s = 0; s < 6; ++s) {
            s16x8 b  = *(const s16x8*)(B_lds + (w * 16 + row) * LSTR + s * 32 + kq);
            s16x8 a0 = *(const s16x8*)(A_lds + row * LSTR + s * 32 + kq);
            s16x8 a1 = *(const s16x8*)(A_lds + (16 + row) * LSTR + s * 32 + kq);
            acc0 = __builtin_amdgcn_mfma_f32_16x16x32_bf16(a0, b, acc0, 0, 0, 0);
            acc1 = __builtin_amdgcn_mfma_f32_16x16x32_bf16(a1, b, acc1, 0, 0, 0);
        }
    }

    int dbase = w << 4;
    #pragma unroll
    for (int r = 0; r < 4; ++r) {
        int m0 = m_base + quad * 4 + r;
        int m1 = m0 + 16;
        if (m0 < MPTS) out[(size_t)m0 * 64 + dbase + row] = acc0[r];
        if (m1 < MPTS) out[(size_t)m1 * 64 + dbase + row] = acc1[r];
    }
}

// ---- fused fallback (R9, proven) --------------------------------------------
template <bool USE_BF>
__device__ __forceinline__
void kpconv_body(const float* __restrict__ q_points,
                 const float* __restrict__ s_points,
                 const float* __restrict__ s_feats,
                 const unsigned short* __restrict__ fbf,
                 const int* __restrict__ ni,
                 const float* __restrict__ kpts,
                 const unsigned short* __restrict__ WT,
                 const unsigned char* __restrict__ signs,
                 float* __restrict__ out) {
    __shared__ __align__(16) unsigned short P_sh[16][PSTRIDE];
    __shared__ __align__(16) float rpos_sh[4][3][32];
    __shared__ int ni_sh[4][4][32];
    __shared__ float kp_sh[16][3];
    __shared__ float q_sh[16][3];
    __shared__ float inv_nnum[16];

    int tid = threadIdx.x, w = tid >> 6, lane = tid & 63;
    int m_base = blockIdx.x << 4;

    if (tid < 48) {
        kp_sh[tid / 3][tid % 3] = (tid < 45) ? kpts[tid] : 1e9f;
        q_sh[tid / 3][tid % 3] = q_points[m_base * 3 + tid];
    }
    __syncthreads();

    int h = lane & 31;
    int row = lane & 15, quad = lane >> 4, kq = quad << 3;
    int h2 = lane >> 1, half = lane & 1;

    float kx = kp_sh[row][0], ky = kp_sh[row][1], kz = kp_sh[row][2];

    float tkx[8], tky[8], tkz[8];
    #pragma unroll
    for (int j = 0; j < 8; ++j) {
        int k = half * 8 + j;
        tkx[j] = kp_sh[k][0]; tky[j] = kp_sh[k][1]; tkz[j] = kp_sh[k][2];
    }

    int idx4[4]; float rxa[4], rya[4], rza[4]; unsigned char sg4[4];
    #pragma unroll
    for (int mi = 0; mi < 4; ++mi)
        idx4[mi] = ni[(m_base + mi * 4 + w) * HN + h];
    #pragma unroll
    for (int mi = 0; mi < 4; ++mi) {
        int m_l = mi * 4 + w;
        bool valid = idx4[mi] < NPTS;
        const float* sp = s_points + (size_t)(valid ? idx4[mi] : 0) * 3;
        float px = sp[0], py = sp[1], pz = sp[2];
        unsigned char sg = signs[valid ? idx4[mi] : 0];
        rxa[mi] = (valid ? px : 1e6f) - q_sh[m_l][0];
        rya[mi] = (valid ? py : 1e6f) - q_sh[m_l][1];
        rza[mi] = (valid ? pz : 1e6f) - q_sh[m_l][2];
        sg4[mi] = valid ? sg : 0;
    }

    #pragma unroll
    for (int mi = 0; mi < 4; ++mi) {
        float rx2 = __shfl(rxa[mi], h2);
        float ry2 = __shfl(rya[mi], h2);
        float rz2 = __shfl(rza[mi], h2);
        int idx2 = __shfl(idx4[mi], h2);
        int av = 0;
        #pragma unroll
        for (int j = 0; j < 8; ++j) {
            float dx = rx2 - tkx[j], dy = ry2 - tky[j], dz = rz2 - tkz[j];
            float d2 = dx * dx + dy * dy + dz * dz;
            av |= (d2 < 1.f) ? 1 : 0;
        }
        av |= __shfl_xor(av, 1);
        bool alive = (idx2 < NPTS) && (av != 0);
        if (half == 0) ni_sh[w][mi][h2] = alive ? idx2 : NPTS;

        unsigned long long pm = __ballot((lane < 32) && (idx4[mi] < NPTS) && sg4[mi]);
        if (lane == 0) {
            int cnt = __popcll(pm);
            inv_nnum[mi * 4 + w] = 1.f / (float)(cnt < 1 ? 1 : cnt);
        }
    }

    #pragma unroll
    for (int mi = 0; mi < 4; ++mi) {
        int m_l = mi * 4 + w;
        if (lane < 32) {
            rpos_sh[w][0][h] = rxa[mi];
            rpos_sh[w][1][h] = rya[mi];
            rpos_sh[w][2][h] = rza[mi];
        }

        float g0[8], g1[8], g2[8], g3[8];
        unsigned d0[8], d1[8];
        #pragma unroll
        for (int j = 0; j < 8; ++j) {
            int idxj = ni_sh[w][mi][kq + j];
            if (USE_BF) {
                d0[j] = 0u; d1[j] = 0u;
                if (idxj < NPTS) {
                    uint2 v = *(const uint2*)(fbf + (size_t)idxj * 64 + row * 4);
                    d0[j] = v.x; d1[j] = v.y;
                }
            } else {
                g0[j] = 0.f; g1[j] = 0.f; g2[j] = 0.f; g3[j] = 0.f;
                if (idxj < NPTS) {
                    const float* fp = s_feats + (size_t)idxj * 64 + row;
                    g0[j] = fp[0]; g1[j] = fp[16]; g2[j] = fp[32]; g3[j] = fp[48];
                }
            }
        }

        float4 ra0 = *(const float4*)&rpos_sh[w][0][kq];
        float4 ra1 = *(const float4*)&rpos_sh[w][0][kq + 4];
        float4 rb0 = *(const float4*)&rpos_sh[w][1][kq];
        float4 rb1 = *(const float4*)&rpos_sh[w][1][kq + 4];
        float4 rc0 = *(const float4*)&rpos_sh[w][2][kq];
        float4 rc1 = *(const float4*)&rpos_sh[w][2][kq + 4];
        float hx[8] = {ra0.x, ra0.y, ra0.z, ra0.w, ra1.x, ra1.y, ra1.z, ra1.w};
        float hy[8] = {rb0.x, rb0.y, rb0.z, rb0.w, rb1.x, rb1.y, rb1.z, rb1.w};
        float hz[8] = {rc0.x, rc0.y, rc0.z, rc0.w, rc1.x, rc1.y, rc1.z, rc1.w};
        float infl[8];
        #pragma unroll
        for (int j = 0; j < 8; ++j) {
            float dx = hx[j] - kx, dy = hy[j] - ky, dz = hz[j] - kz;
            float d2 = dx * dx + dy * dy + dz * dz;
            float f = 1.f - sqrtf(d2);
            infl[j] = f > 0.f ? f : 0.f;
        }
        union { unsigned u[4]; s16x8 v; } af;
        #pragma unroll
        for (int p = 0; p < 4; ++p) af.u[p] = pack_bf(infl[2 * p], infl[2 * p + 1]);

        #pragma unroll
        for (int ch = 0; ch < 4; ++ch) {
            union { unsigned u[4]; s16x8 v; } bfr;
            if (USE_BF) {
                #pragma unroll
                for (int p = 0; p < 4; ++p) {
                    unsigned a = (ch < 2) ? d0[2 * p] : d1[2 * p];
                    unsigned b = (ch < 2) ? d0[2 * p + 1] : d1[2 * p + 1];
                    bfr.u[p] = (ch & 1) ? pack_hi16(a, b) : pack_lo16(a, b);
                }
            } else {
                const float* gs = (ch == 0) ? g0 : (ch == 1) ? g1 : (ch == 2) ? g2 : g3;
                #pragma unroll
                for (int p = 0; p < 4; ++p) bfr.u[p] = pack_bf(gs[2 * p], gs[2 * p + 1]);
            }
            f32x4 acc = {0.f, 0.f, 0.f, 0.f};
            acc = __builtin_amdgcn_mfma_f32_16x16x32_bf16(af.v, bfr.v, acc, 0, 0, 0);
            int cc = ch * 16 + row;
            #pragma unroll
            for (int r = 0; r < 4; ++r) {
                int k2 = quad * 4 + r;
                if (k2 < 15) {
                    int col = (k2 << 6) | (cc ^ ((k2 >> 2) << 4));
                    P_sh[m_l][col] = bf_trunc(acc[r]);
                }
            }
        }
    }
    __syncthreads();

    {
        int dbase = w << 4;
        f32x4 acc = {0.f, 0.f, 0.f, 0.f};
        const unsigned short* wtp = WT + (size_t)(dbase + row) * KCD + kq;
        #pragma unroll 6
        for (int s = 0; s < 30; ++s) {
            int k = s >> 1;
            int c0 = ((s & 1) << 5) + kq;
            int cx = c0 ^ (((k >> 2) & 3) << 4);
            s16x8 a = *(const s16x8*)&P_sh[row][(k << 6) | cx];
            s16x8 b = *(const s16x8*)&wtp[s * 32];
            acc = __builtin_amdgcn_mfma_f32_16x16x32_bf16(a, b, acc, 0, 0, 0);
        }
        #pragma unroll
        for (int r = 0; r < 4; ++r) {
            int m_l = quad * 4 + r;
            out[(size_t)(m_base + m_l) * 64 + dbase + row] = acc[r] * inv_nnum[m_l];
        }
    }
}

__global__ __launch_bounds__(256, 4)
void kpconv_main_bf(const float* __restrict__ q, const float* __restrict__ sp,
                    const unsigned short* __restrict__ fbf,
                    const int* __restrict__ ni, const float* __restrict__ kp,
                    const unsigned short* __restrict__ WT,
                    const unsigned char* __restrict__ signs,
                    float* __restrict__ out) {
    kpconv_body<true>(q, sp, nullptr, fbf, ni, kp, WT, signs, out);
}

__global__ __launch_bounds__(256, 4)
void kpconv_main_f32(const float* __restrict__ q, const float* __restrict__ sp,
                     const float* __restrict__ sf,
                     const int* __restrict__ ni, const float* __restrict__ kp,
                     const unsigned short* __restrict__ WT,
                     const unsigned char* __restrict__ signs,
                     float* __restrict__ out) {
    kpconv_body<false>(q, sp, sf, nullptr, ni, kp, WT, signs, out);
}

extern "C" void kernel_launch(void* const* d_in, const int* in_sizes, int n_in,
                              void* d_out, int out_size, void* d_ws, size_t ws_size,
                              hipStream_t stream) {
    const float* q  = (const float*)d_in[0];
    const float* sp = (const float*)d_in[1];
    const float* sf = (const float*)d_in[2];
    const int*   ni = (const int*)d_in[3];
    const float* kp = (const float*)d_in[4];
    const float* wt = (const float*)d_in[5];
    float* out = (float*)d_out;

    unsigned short* WT = (unsigned short*)d_ws;                     // 122880 B
    unsigned char* signs = (unsigned char*)d_ws + 122880;           // 50000 B
    const size_t off_spt = 172928;
    float4* spt4 = (float4*)((char*)d_ws + off_spt);                // 800000 B
    const size_t off_fbf = off_spt + (size_t)NPTS * 16;             // 972928
    unsigned short* fbf = (unsigned short*)((char*)d_ws + off_fbf); // 6.4 MB
    const size_t off_P = off_fbf + (size_t)NPTS * 64 * 2;           // 7372928
    unsigned short* P = (unsigned short*)((char*)d_ws + off_P);     // 96 MB (+pad)
    const size_t need_bf = off_P;
    const size_t need_split = off_P + (size_t)MPAD * KCD * 2;

    if (ws_size >= need_split) {
        hipLaunchKernelGGL(prep_bf, dim3(240 + NPTS / 16), dim3(256), 0, stream,
                           wt, sf, sp, WT, signs, spt4, fbf);
        hipLaunchKernelGGL(kpconv_p1, dim3(MPTS / 16), dim3(256), 0, stream,
                           q, spt4, fbf, ni, kp, P);
        hipLaunchKernelGGL(kpconv_p2, dim3((MPTS + 31) / 32), dim3(256), 0, stream,
                           P, WT, out);
    } else if (ws_size >= need_bf) {
        hipLaunchKernelGGL(prep_bf, dim3(240 + NPTS / 16), dim3(256), 0, stream,
                           wt, sf, sp, WT, signs, spt4, fbf);
        hipLaunchKernelGGL(kpconv_main_bf, dim3(MPTS / 16), dim3(256), 0, stream,
                           q, sp, fbf, ni, kp, WT, signs, out);
    } else {
        hipLaunchKernelGGL(prep_f32, dim3(240 + NPTS / 16), dim3(256), 0, stream,
                           wt, sf, WT, signs);
        hipLaunchKernelGGL(kpconv_main_f32, dim3(MPTS / 16), dim3(256), 0, stream,
                           q, sp, sf, ni, kp, WT, signs, out);
    }
}